// Round 5
// baseline (855.091 us; speedup 1.0000x reference)
//
#include <hip/hip_runtime.h>

// ---------------- types / helpers ----------------
typedef unsigned short u16;
typedef __bf16 bf16x8 __attribute__((ext_vector_type(8)));
typedef float floatx4 __attribute__((ext_vector_type(4)));

#define DIM 512
#define HEADS 8
#define DH 64
#define SEQ 4096
#define BATCH 2
#define ROWS (BATCH * SEQ) /* 8192 */
#define FFDIM 2048
#define QKVW 1536 /* fused qkv row width */
#define LSTRIDE 3145728L /* repacked weight elems per layer */

__device__ __forceinline__ float b2f(u16 u) {
  union { float f; unsigned int i; } c; c.i = ((unsigned int)u) << 16; return c.f;
}
__device__ __forceinline__ u16 f2b(float f) {
  union { float f; unsigned int i; } c; c.f = f;
  unsigned int r = c.i + 0x7FFFu + ((c.i >> 16) & 1u);
  return (u16)(r >> 16);
}
__device__ __forceinline__ float ldin(const void* p, long i, int bf) {
  return bf ? b2f(((const u16*)p)[i]) : ((const float*)p)[i];
}
// async global->LDS, 16 bytes/lane. LDS dest = base + lane*16 (HW); global addr per-lane.
__device__ __forceinline__ void ld16(const u16* g, u16* l) {
  __builtin_amdgcn_global_load_lds((const __attribute__((address_space(1))) void*)g,
                                   (__attribute__((address_space(3))) void*)l, 16, 0, 0);
}
// unpack 8 u16 (as uint4) -> 8 floats
__device__ __forceinline__ void unpk8(uint4 p, float* o) {
  o[0] = b2f((u16)(p.x & 0xFFFF)); o[1] = b2f((u16)(p.x >> 16));
  o[2] = b2f((u16)(p.y & 0xFFFF)); o[3] = b2f((u16)(p.y >> 16));
  o[4] = b2f((u16)(p.z & 0xFFFF)); o[5] = b2f((u16)(p.z >> 16));
  o[6] = b2f((u16)(p.w & 0xFFFF)); o[7] = b2f((u16)(p.w >> 16));
}
// exact-enough GELU: erf via Abramowitz-Stegun 7.1.26 (|err| <= 1.5e-7) + fast exp.
__device__ __forceinline__ float fast_gelu(float v) {
  float z = fabsf(v) * 0.70710678118654752f;
  float t = 1.0f / (1.0f + 0.3275911f * z);
  float p = t * (0.254829592f +
           t * (-0.284496736f +
           t * (1.421413741f +
           t * (-1.453152027f +
           t * 1.061405429f))));
  float e = __expf(-z * z);
  float er = 1.0f - p * e;             // erf(|z|)
  float s = copysignf(er, v);          // erf(z)
  return 0.5f * v * (1.0f + s);
}

// ---------------- dtype detection ----------------
__global__ void k_detect(const void* __restrict__ g, int* __restrict__ flag) {
  *flag = (((const u16*)g)[0] == 0x3F80u) ? 1 : 0;
}

// ---------------- input x -> f32 / f32 -> out ----------------
__global__ __launch_bounds__(256) void k_x2f(const void* __restrict__ in, float* __restrict__ out,
                                             int n, const int* __restrict__ dt) {
  int bf = *dt;
  int i = blockIdx.x * 256 + threadIdx.x;
  if (i < n) out[i] = ldin(in, i, bf);
}
__global__ __launch_bounds__(256) void k_store(const float* __restrict__ in, void* __restrict__ out,
                                               int n, const int* __restrict__ dt) {
  int bf = *dt;
  int i = blockIdx.x * 256 + threadIdx.x;
  if (i < n) {
    if (bf) ((u16*)out)[i] = f2b(in[i]);
    else ((float*)out)[i] = in[i];
  }
}

// ---------------- weight repack (LDS-tiled, coalesced, batched) ----------------
__device__ __forceinline__ void repack_tile(const void* W, long w_off, u16* R, int N,
                                            int n16tot, int j_off, int kb, int jb, int bf) {
  int t = threadIdx.x;
  __shared__ float tile[32][65];
  int r0 = t >> 6;
  int c = t & 63;
#pragma unroll
  for (int i = 0; i < 8; ++i) {
    int rr = i * 4 + r0;
    tile[rr][c] = ldin(W, w_off + (long)(kb * 32 + rr) * N + jb * 64 + c, bf);
  }
  __syncthreads();
  int lane = t & 63, w = t >> 6;
  alignas(16) u16 tmp[8];
#pragma unroll
  for (int r = 0; r < 8; ++r) tmp[r] = f2b(tile[(lane >> 4) * 8 + r][w * 16 + (lane & 15)]);
  long oidx = (((long)kb * n16tot + j_off + jb * 4 + w) * 64 + lane) * 8;
  *(uint4*)(R + oidx) = *(const uint4*)tmp;
}
// all 512x512 weights: grid (16,8,16); z = layer*4 + type(0=q,1=k,2=v,3=o)
__global__ __launch_bounds__(256) void k_repackQ(const void* wq, const void* wk,
                                                 const void* wv, const void* wo,
                                                 u16* WR, const int* __restrict__ dt) {
  int bf = *dt;
  int z = blockIdx.z, layer = z >> 2, type = z & 3;
  const void* W = (type == 0) ? wq : (type == 1) ? wk : (type == 2) ? wv : wo;
  u16* R = WR + (long)layer * LSTRIDE + (type < 3 ? 0 : 786432);
  int n16tot = (type < 3) ? 96 : 32;
  int j_off = (type < 3) ? type * 32 : 0;
  repack_tile(W, (long)layer * 262144, R, 512, n16tot, j_off, blockIdx.x, blockIdx.y, bf);
}
// w1: grid (16,32,4)
__global__ __launch_bounds__(256) void k_repackF1(const void* w1, u16* WR, const int* __restrict__ dt) {
  int bf = *dt;
  repack_tile(w1, (long)blockIdx.z * 1048576, WR + (long)blockIdx.z * LSTRIDE + 1048576,
              2048, 128, 0, blockIdx.x, blockIdx.y, bf);
}
// w2: grid (64,8,4)
__global__ __launch_bounds__(256) void k_repackF2(const void* w2, u16* WR, const int* __restrict__ dt) {
  int bf = *dt;
  repack_tile(w2, (long)blockIdx.z * 1048576, WR + (long)blockIdx.z * LSTRIDE + 2097152,
              512, 32, 0, blockIdx.x, blockIdx.y, bf);
}

// ---------------- layernorm (f32 in, bf16 out) ----------------
__global__ __launch_bounds__(256) void k_ln(const float* __restrict__ x,
                                            const void* __restrict__ g, const void* __restrict__ b,
                                            long gb_off, u16* __restrict__ out,
                                            const int* __restrict__ dt) {
  int bf = *dt;
  int row = blockIdx.x;
  int t = threadIdx.x;
  const float* xr = x + (size_t)row * DIM;
  float v0 = xr[t], v1 = xr[t + 256];
  float s = v0 + v1;
  float s2 = v0 * v0 + v1 * v1;
#pragma unroll
  for (int off = 32; off > 0; off >>= 1) {
    s += __shfl_down(s, off);
    s2 += __shfl_down(s2, off);
  }
  __shared__ float red[8];
  int lane = t & 63, w = t >> 6;
  if (lane == 0) { red[w] = s; red[4 + w] = s2; }
  __syncthreads();
  float ts = red[0] + red[1] + red[2] + red[3];
  float ts2 = red[4] + red[5] + red[6] + red[7];
  float mean = ts * (1.0f / DIM);
  float var = ts2 * (1.0f / DIM) - mean * mean;
  float rstd = rsqrtf(var + 1e-5f);
  u16* orow = out + (size_t)row * DIM;
  orow[t] = f2b((v0 - mean) * rstd * ldin(g, gb_off + t, bf) + ldin(b, gb_off + t, bf));
  orow[t + 256] = f2b((v1 - mean) * rstd * ldin(g, gb_off + t + 256, bf) + ldin(b, gb_off + t + 256, bf));
}

// ---------------- MFMA GEMM v3.1 (N=512 GEMMs: WO, W2) — BK=64 ----------------
template <int NJ, bool HAS_BIAS, bool DO_GELU, bool HAS_RES, bool OUT_F32>
__global__ __launch_bounds__(256) void k_gemm3(const u16* __restrict__ A, const u16* __restrict__ BR,
                                               const void* bias, long bias_off,
                                               const float* res, void* outp,
                                               int M, int N, int K, const int* dtflag) {
  int lane = threadIdx.x & 63;
  int wid = threadIdx.x >> 6;
  int wm = wid & 1, wn = wid >> 1;
  int m0 = blockIdx.x * 128;
  int n0 = blockIdx.y * (NJ * 32);
  int n16 = N >> 4;
  int n016 = n0 >> 4;

  constexpr int BUFB = (16 + 4 * NJ) * 1024;  // A 16KB + B NJ*4KB per buffer
  __shared__ alignas(16) char smem[2 * BUFB];

  floatx4 acc[4][NJ];
#pragma unroll
  for (int mi = 0; mi < 4; ++mi)
#pragma unroll
    for (int j = 0; j < NJ; ++j)
#pragma unroll
      for (int r = 0; r < 4; ++r) acc[mi][j][r] = 0.0f;

  const u16* Ag = A + ((size_t)(m0 + wid * 32 + (lane & 15)) * K + ((lane >> 4) * 8));
  int nKB = K >> 6;

  auto stage = [&](int kb, int b) {
    u16* aL = (u16*)(smem + b * BUFB);
    u16* bL = aL + 8192;
    const u16* s = Ag + (size_t)kb * 64;
    ld16(s,                        aL + (wid * 2) * 512);            // kk0, rows lo
    ld16(s + (size_t)16 * K,       aL + (wid * 2 + 1) * 512);        // kk0, rows hi
    ld16(s + 32,                   aL + 4096 + (wid * 2) * 512);     // kk1, rows lo
    ld16(s + (size_t)16 * K + 32,  aL + 4096 + (wid * 2 + 1) * 512); // kk1, rows hi
#pragma unroll
    for (int sj = 0; sj < NJ / 2; ++sj) {
      int jg = wid * (NJ / 2) + sj;
      ld16(BR + (((size_t)(kb * 2) * n16 + n016 + jg) * 64 + lane) * 8, bL + jg * 512);
      ld16(BR + (((size_t)(kb * 2 + 1) * n16 + n016 + jg) * 64 + lane) * 8,
           bL + NJ * 1024 + jg * 512);
    }
  };

  stage(0, 0);
  for (int kb = 0; kb < nKB; ++kb) {
    __syncthreads();  // compiler drains vmcnt: stage(kb) complete, prev reads done
    if (kb + 1 < nKB) stage(kb + 1, (kb + 1) & 1);
    const u16* aL = (const u16*)(smem + (kb & 1) * BUFB);
    const u16* bL = aL + 8192;
#pragma unroll
    for (int h = 0; h < 2; ++h) {
      bf16x8 afr[4], bfr[NJ];
#pragma unroll
      for (int mi = 0; mi < 4; ++mi)
        afr[mi] = *(const bf16x8*)(aL + h * 4096 + ((wm * 4 + mi) * 64 + lane) * 8);
#pragma unroll
      for (int j = 0; j < NJ; ++j)
        bfr[j] = *(const bf16x8*)(bL + h * NJ * 1024 + ((wn * NJ + j) * 64 + lane) * 8);
#pragma unroll
      for (int mi = 0; mi < 4; ++mi)
#pragma unroll
        for (int j = 0; j < NJ; ++j)
          acc[mi][j] = __builtin_amdgcn_mfma_f32_16x16x32_bf16(afr[mi], bfr[j], acc[mi][j], 0, 0, 0);
    }
  }

  // ---- epilogue: per-wave LDS transpose -> coalesced vector stores ----
  __syncthreads();
  constexpr int EPS = 84;
  float* ep = (float*)smem + wid * (16 * EPS);
  constexpr int C = NJ * 16;
  int dtv = HAS_BIAS ? *dtflag : 0;
  int nW = n0 + wn * C;
  int mWbase = m0 + wm * 64;

#pragma unroll
  for (int mi = 0; mi < 4; ++mi) {
#pragma unroll
    for (int j = 0; j < NJ; ++j) {
      float bv = HAS_BIAS ? ldin(bias, bias_off + nW + j * 16 + (lane & 15), dtv) : 0.0f;
#pragma unroll
      for (int r = 0; r < 4; ++r) {
        float v = acc[mi][j][r] + bv;
        if (DO_GELU) v = fast_gelu(v);
        ep[((lane >> 4) * 4 + r) * EPS + j * 16 + (lane & 15)] = v;
      }
    }
    __builtin_amdgcn_s_waitcnt(0);
    if (OUT_F32) {
      constexpr int LPR = C / 4;
      constexpr int RPP = 64 / LPR;
      constexpr int NP = 16 / RPP;
#pragma unroll
      for (int p = 0; p < NP; ++p) {
        int row = p * RPP + lane / LPR;
        int cb = (lane % LPR) * 4;
        float4 v = *(const float4*)&ep[row * EPS + cb];
        size_t gi = (size_t)(mWbase + mi * 16 + row) * N + nW + cb;
        if (HAS_RES) {
          float4 rv = *(const float4*)&res[gi];
          v.x += rv.x; v.y += rv.y; v.z += rv.z; v.w += rv.w;
        }
        *(float4*)&((float*)outp)[gi] = v;
      }
    } else {
      constexpr int LPR = C / 8;
      constexpr int RPP = 64 / LPR;
      constexpr int NP = 16 / RPP;
#pragma unroll
      for (int p = 0; p < NP; ++p) {
        int row = p * RPP + lane / LPR;
        int cb = (lane % LPR) * 8;
        const float* er = &ep[row * EPS + cb];
        uint4 pk;
        pk.x = (unsigned)f2b(er[0]) | ((unsigned)f2b(er[1]) << 16);
        pk.y = (unsigned)f2b(er[2]) | ((unsigned)f2b(er[3]) << 16);
        pk.z = (unsigned)f2b(er[4]) | ((unsigned)f2b(er[5]) << 16);
        pk.w = (unsigned)f2b(er[6]) | ((unsigned)f2b(er[7]) << 16);
        size_t gi = (size_t)(mWbase + mi * 16 + row) * N + nW + cb;
        *(uint4*)&((u16*)outp)[gi] = pk;
      }
    }
    __builtin_amdgcn_s_waitcnt(0);
  }
}

// ---------------- MFMA GEMM v4.4: 256x256 pipeline, pinned schedule ----------------
// Same algorithm as v4.3 (round 3) with two fixes:
//  (a) each template instantiation gets its OWN named __global__ (independent
//      regalloc/scheduling; rule #19 co-compilation perturbation) and shows up
//      distinctly in the profile;
//  (b) sched_barrier(0) pins every phase boundary and brackets each MFMA cluster
//      (rule #18: inline-asm waitcnts do NOT order register-only MFMA; without
//      pinning, the scheduler can migrate MFMA clusters / stage issues across
//      phases and wreck the counted-vmcnt pipeline).
#define SBAR0() __builtin_amdgcn_sched_barrier(0)

template <bool HAS_BIAS, bool DO_GELU>
__device__ __forceinline__ void gemm8_body(const u16* __restrict__ A, const u16* __restrict__ BR,
                                           const void* bias, long bias_off,
                                           u16* __restrict__ outp,
                                           int N, int K, const int* dtflag) {
  int lane = threadIdx.x & 63;
  int w = threadIdx.x >> 6;       // wave 0..7
  int wm = w >> 2, wn = w & 3;    // 2 x 4
  int m0 = blockIdx.x * 256;
  int n0 = blockIdx.y * 256;
  int n16 = N >> 4;
  int n016 = n0 >> 4;
  int NKT = K >> 6;               // K-tiles of 64

  __shared__ alignas(16) u16 smem8[65536];  // 2 bufs x (A 32KB | B 32KB) = 128 KiB

  // ---- A staging bases (contiguous + pre-swizzled source) ----
  int arow = lane >> 3;                       // row within 8-row inst group
  int acu = ((lane & 7) ^ arow) * 8;          // pre-swizzled col (u16 units)
  const u16* Ag0 = A + (size_t)(m0 + (w * 2 + 0) * 8 + arow) * K + acu;
  const u16* Ag1 = A + (size_t)(m0 + (w * 2 + 1) * 8 + arow) * K + acu;
  const u16* Bg = BR + (size_t)n016 * 512 + lane * 8;

  // stage A half (rows half*128..+127) of K-tile kt: 2 insts, 8 rows x 128B each
  auto stA = [&](int kt, int half, int dbuf) {
    u16* dst = smem8 + dbuf * 32768 + half * 8192;
    size_t go = (size_t)half * 128 * K + (size_t)kt * 64;
    ld16(Ag0 + go, dst + (w * 2 + 0) * 512);
    ld16(Ag1 + go, dst + (w * 2 + 1) * 512);
  };
  // stage B kk-half of K-tile kt: 2 insts (col-groups j=w, j=8+w)
  auto stB = [&](int kt, int kk, int dbuf) {
    u16* dst = smem8 + dbuf * 32768 + 16384 + kk * 8192;
    const u16* s = Bg + ((size_t)(kt * 2 + kk) * n16) * 512;
    ld16(s + (size_t)w * 512,       dst + (0 + w) * 512);
    ld16(s + (size_t)(8 + w) * 512, dst + (8 + w) * 512);
  };

  // per-lane swizzled A-read offsets (u16 units)
  int aoff = (lane & 15) * 64;
  int axor = (lane & 7) << 3;
  int ak0 = (((lane >> 4) * 8)) ^ axor;        // kk0 col part
  int ak1 = ((32 + (lane >> 4) * 8)) ^ axor;   // kk1 col part

  floatx4 acc[8][4];
#pragma unroll
  for (int mi = 0; mi < 8; ++mi)
#pragma unroll
    for (int j = 0; j < 4; ++j)
#pragma unroll
      for (int r = 0; r < 4; ++r) acc[mi][j][r] = 0.0f;

  // ---- prologue: K-tile 0 fully staged; leave B-kk1(0) in flight ----
  stA(0, 0, 0);
  stA(0, 1, 0);
  stB(0, 0, 0);
  stB(0, 1, 0);
  SBAR0();
  asm volatile("s_waitcnt vmcnt(2)" ::: "memory");
  SBAR0();
  __builtin_amdgcn_s_barrier();

  for (int c = 0; c < NKT; ++c) {
    int buf = c & 1;
    const u16* aL = smem8 + buf * 32768;
    const u16* bL = aL + 16384;
    int kt1 = (c + 1 < NKT) ? c + 1 : NKT - 1;  // clamped (dummy re-stage at tail)
    bf16x8 afr[4], bfr[4];

    // ---- phase 0: (kk0, mh0) ----
#pragma unroll
    for (int i = 0; i < 4; ++i)
      afr[i] = *(const bf16x8*)(aL + (wm * 8 + i) * 1024 + aoff + ak0);
#pragma unroll
    for (int i = 0; i < 4; ++i)
      bfr[i] = *(const bf16x8*)(bL + ((wn * 4 + i) * 64 + lane) * 8);
    stA(kt1, 0, buf ^ 1);
    SBAR0();
    __builtin_amdgcn_s_barrier();
    asm volatile("s_waitcnt lgkmcnt(0)" ::: "memory");
    SBAR0();
    __builtin_amdgcn_s_setprio(1);
#pragma unroll
    for (int mi = 0; mi < 4; ++mi)
#pragma unroll
      for (int j = 0; j < 4; ++j)
        acc[mi][j] = __builtin_amdgcn_mfma_f32_16x16x32_bf16(afr[mi], bfr[j], acc[mi][j], 0, 0, 0);
    __builtin_amdgcn_s_setprio(0);
    SBAR0();
    __builtin_amdgcn_s_barrier();

    // ---- phase 1: (kk0, mh1) ----
#pragma unroll
    for (int i = 0; i < 4; ++i)
      afr[i] = *(const bf16x8*)(aL + (wm * 8 + 4 + i) * 1024 + aoff + ak0);
    stA(kt1, 1, buf ^ 1);
    SBAR0();
    __builtin_amdgcn_s_barrier();
    asm volatile("s_waitcnt lgkmcnt(0)" ::: "memory");
    SBAR0();
    __builtin_amdgcn_s_setprio(1);
#pragma unroll
    for (int mi = 0; mi < 4; ++mi)
#pragma unroll
      for (int j = 0; j < 4; ++j)
        acc[4 + mi][j] = __builtin_amdgcn_mfma_f32_16x16x32_bf16(afr[mi], bfr[j], acc[4 + mi][j], 0, 0, 0);
    __builtin_amdgcn_s_setprio(0);
    SBAR0();
    // B-kk1(c) (staged last iter) must land before ph2 reads; 4 younger loads fly on
    asm volatile("s_waitcnt vmcnt(4)" ::: "memory");
    SBAR0();
    __builtin_amdgcn_s_barrier();

    // ---- phase 2: (kk1, mh0) ----
#pragma unroll
    for (int i = 0; i < 4; ++i)
      afr[i] = *(const bf16x8*)(aL + (wm * 8 + i) * 1024 + aoff + ak1);
#pragma unroll
    for (int i = 0; i < 4; ++i)
      bfr[i] = *(const bf16x8*)(bL + ((16 + wn * 4 + i) * 64 + lane) * 8);
    stB(kt1, 0, buf ^ 1);
    SBAR0();
    __builtin_amdgcn_s_barrier();
    asm volatile("s_waitcnt lgkmcnt(0)" ::: "memory");
    SBAR0();
    __builtin_amdgcn_s_setprio(1);
#pragma unroll
    for (int mi = 0; mi < 4; ++mi)
#pragma unroll
      for (int j = 0; j < 4; ++j)
        acc[mi][j] = __builtin_amdgcn_mfma_f32_16x16x32_bf16(afr[mi], bfr[j], acc[mi][j], 0, 0, 0);
    __builtin_amdgcn_s_setprio(0);
    SBAR0();
    __builtin_amdgcn_s_barrier();

    // ---- phase 3: (kk1, mh1) ----
#pragma unroll
    for (int i = 0; i < 4; ++i)
      afr[i] = *(const bf16x8*)(aL + (wm * 8 + 4 + i) * 1024 + aoff + ak1);
    stB(kt1, 1, buf ^ 1);
    SBAR0();
    __builtin_amdgcn_s_barrier();
    asm volatile("s_waitcnt lgkmcnt(0)" ::: "memory");
    SBAR0();
    __builtin_amdgcn_s_setprio(1);
#pragma unroll
    for (int mi = 0; mi < 4; ++mi)
#pragma unroll
      for (int j = 0; j < 4; ++j)
        acc[4 + mi][j] = __builtin_amdgcn_mfma_f32_16x16x32_bf16(afr[mi], bfr[j], acc[4 + mi][j], 0, 0, 0);
    __builtin_amdgcn_s_setprio(0);
    SBAR0();
    // A(c+1) + B-kk0(c+1) must land before next ph0; B-kk1(c+1) stays in flight
    asm volatile("s_waitcnt vmcnt(2)" ::: "memory");
    SBAR0();
    __builtin_amdgcn_s_barrier();
  }

  // drain tail stages before reusing LDS
  asm volatile("s_waitcnt vmcnt(0)" ::: "memory");
  SBAR0();
  __builtin_amdgcn_s_barrier();

  // ---- epilogue: per-wave LDS transpose -> coalesced bf16 stores ----
  constexpr int EPS = 68;
  float* ep = (float*)smem8 + w * (16 * EPS);
  int dtv = HAS_BIAS ? *dtflag : 0;
  int nW = n0 + wn * 64;
  int mW = m0 + wm * 128;

#pragma unroll
  for (int mf = 0; mf < 8; ++mf) {
#pragma unroll
    for (int j = 0; j < 4; ++j) {
      float bv = HAS_BIAS ? ldin(bias, bias_off + nW + j * 16 + (lane & 15), dtv) : 0.0f;
#pragma unroll
      for (int r = 0; r < 4; ++r) {
        float v = acc[mf][j][r] + bv;
        if (DO_GELU) v = fast_gelu(v);
        ep[((lane >> 4) * 4 + r) * EPS + j * 16 + (lane & 15)] = v;
      }
    }
    asm volatile("s_waitcnt lgkmcnt(0)" ::: "memory");
#pragma unroll
    for (int p = 0; p < 2; ++p) {
      int row = p * 8 + (lane >> 3);
      int cb = (lane & 7) * 8;
      const float* er = &ep[row * EPS + cb];
      uint4 pk;
      pk.x = (unsigned)f2b(er[0]) | ((unsigned)f2b(er[1]) << 16);
      pk.y = (unsigned)f2b(er[2]) | ((unsigned)f2b(er[3]) << 16);
      pk.z = (unsigned)f2b(er[4]) | ((unsigned)f2b(er[5]) << 16);
      pk.w = (unsigned)f2b(er[6]) | ((unsigned)f2b(er[7]) << 16);
      size_t gi = (size_t)(mW + mf * 16 + row) * N + nW + cb;
      *(uint4*)&outp[gi] = pk;
    }
    asm volatile("s_waitcnt lgkmcnt(0)" ::: "memory");
  }
}

// separately-named instantiations (independent codegen, distinct profile rows)
__global__ __launch_bounds__(512, 2) void k_g8a(const u16* __restrict__ A, const u16* __restrict__ BR,
                                                u16* __restrict__ outp, int N, int K,
                                                const int* dtflag) {
  gemm8_body<false, false>(A, BR, nullptr, 0, outp, N, K, dtflag);
}
__global__ __launch_bounds__(512, 2) void k_g8b(const u16* __restrict__ A, const u16* __restrict__ BR,
                                                const void* bias, long bias_off,
                                                u16* __restrict__ outp, int N, int K,
                                                const int* dtflag) {
  gemm8_body<true, true>(A, BR, bias, bias_off, outp, N, K, dtflag);
}

// ---------------- attention phase A: per-bucket exp(k)^T v and key sums ----------------
__global__ __launch_bounds__(256) void k_attnA(const u16* __restrict__ qkv,
                                               float* __restrict__ Ksum, float* __restrict__ KV) {
  int u = blockIdx.x & 63;
  int bh = blockIdx.x >> 6;
  int head = bh & 7, batch = bh >> 3;
  int t = threadIdx.x;
  int pr = t >> 2, s = t & 3;
  __shared__ float kex[64][68];
  __shared__ float vv[64][68];
  const u16* base = qkv + (size_t)(batch * SEQ + u * 64 + pr) * QKVW + head * DH;
  uint4 kp0 = *(const uint4*)(base + 512 + s * 16);
  uint4 kp1 = *(const uint4*)(base + 512 + s * 16 + 8);
  uint4 vp0 = *(const uint4*)(base + 1024 + s * 16);
  uint4 vp1 = *(const uint4*)(base + 1024 + s * 16 + 8);
  float kf[16], vf[16];
  unpk8(kp0, kf); unpk8(kp1, kf + 8);
  unpk8(vp0, vf); unpk8(vp1, vf + 8);
#pragma unroll
  for (int i = 0; i < 16; ++i) {
    kex[pr][s * 16 + i] = expf(fminf(kf[i], 30.0f));
    vv[pr][s * 16 + i] = vf[i];
  }
  __syncthreads();
  int d = pr;
  float acc[16];
#pragma unroll
  for (int i = 0; i < 16; ++i) acc[i] = 0.0f;
  float ks = 0.0f;
  for (int p = 0; p < 64; ++p) {
    float kp = kex[p][d];
    ks += kp;
#pragma unroll
    for (int i4 = 0; i4 < 4; ++i4) {
      float4 v4 = *(const float4*)&vv[p][s * 16 + i4 * 4];
      acc[i4 * 4 + 0] += kp * v4.x;
      acc[i4 * 4 + 1] += kp * v4.y;
      acc[i4 * 4 + 2] += kp * v4.z;
      acc[i4 * 4 + 3] += kp * v4.w;
    }
  }
  float* kvout = KV + (size_t)blockIdx.x * 4096 + d * 64 + s * 16;
#pragma unroll
  for (int i4 = 0; i4 < 4; ++i4) {
    float4 o; o.x = acc[i4 * 4]; o.y = acc[i4 * 4 + 1]; o.z = acc[i4 * 4 + 2]; o.w = acc[i4 * 4 + 3];
    *(float4*)(kvout + i4 * 4) = o;
  }
  if (s == 0) Ksum[(size_t)blockIdx.x * 64 + d] = ks;
}

// ---------------- attention phase B: exclusive prefix over buckets ----------------
__global__ __launch_bounds__(64) void k_scan2(float* __restrict__ Ksum, float* __restrict__ KV) {
  int bh = blockIdx.x >> 6;
  int d = blockIdx.x & 63;
  int e = threadIdx.x;
  float* p0 = KV + (size_t)bh * 64 * 4096 + d * 64 + e;
  float v[64];
#pragma unroll
  for (int u = 0; u < 64; ++u) v[u] = p0[(size_t)u * 4096];
  float run = 0.0f;
#pragma unroll
  for (int u = 0; u < 64; ++u) { float c = v[u]; v[u] = run; run += c; }
#pragma unroll
  for (int u = 0; u < 64; ++u) p0[(size_t)u * 4096] = v[u];
  if (d == 0) {
    float* kp = Ksum + (size_t)bh * 4096 + e;
    float sv[64];
#pragma unroll
    for (int u = 0; u < 64; ++u) sv[u] = kp[u * 64];
    float r = 0.0f;
#pragma unroll
    for (int u = 0; u < 64; ++u) { float c = sv[u]; sv[u] = r; r += c; }
#pragma unroll
    for (int u = 0; u < 64; ++u) kp[u * 64] = sv[u];
  }
}

// ---------------- attention phase C: softmax(q), D, output ----------------
__global__ __launch_bounds__(256) void k_attnC(const u16* __restrict__ qkv, const float* __restrict__ Ksum,
                                               const float* __restrict__ KV, u16* __restrict__ att) {
  int u = blockIdx.x & 63;
  int bh = blockIdx.x >> 6;
  int head = bh & 7, batch = bh >> 3;
  int t = threadIdx.x;
  int pos = t >> 2, s = t & 3;
  __shared__ float Cm[64][68];
  __shared__ float qs[64][68];
  __shared__ float S[64];
  const float* kvb = KV + (size_t)blockIdx.x * 4096 + pos * 64 + s * 16;
#pragma unroll
  for (int i4 = 0; i4 < 4; ++i4)
    *(float4*)&Cm[pos][s * 16 + i4 * 4] = *(const float4*)(kvb + i4 * 4);
  if (t < 64) S[t] = Ksum[(size_t)blockIdx.x * 64 + t];
  size_t grow = (size_t)(batch * SEQ + u * 64 + pos) * QKVW + head * DH;
  uint4 q0 = *(const uint4*)(qkv + grow + s * 16);
  uint4 q1 = *(const uint4*)(qkv + grow + s * 16 + 8);
  float q[16];
  unpk8(q0, q); unpk8(q1, q + 8);
  float mx = q[0];
#pragma unroll
  for (int i = 1; i < 16; ++i) mx = fmaxf(mx, q[i]);
  mx = fmaxf(mx, __shfl_xor(mx, 1));
  mx = fmaxf(mx, __shfl_xor(mx, 2));
  float sum = 0.0f;
#pragma unroll
  for (int i = 0; i < 16; ++i) { q[i] = expf(q[i] - mx); sum += q[i]; }
  sum += __shfl_xor(sum, 1);
  sum += __shfl_xor(sum, 2);
  float scale = 0.125f / sum;  // * e^-0.5 with e=64
  __syncthreads();  // S ready
  float Dp = 0.0f;
#pragma unroll
  for (int i = 0; i < 16; ++i) { q[i] *= scale; Dp += q[i] * S[s * 16 + i]; }
  Dp += __shfl_xor(Dp, 1);
  Dp += __shfl_xor(Dp, 2);
  float Dinv = 1.0f / fmaxf(Dp, 1e-3f);
#pragma unroll
  for (int i = 0; i < 16; ++i) qs[pos][s * 16 + i] = q[i];
  __syncthreads();  // Cm + qs ready
  float o[16];
#pragma unroll
  for (int i = 0; i < 16; ++i) o[i] = 0.0f;
  for (int d = 0; d < 64; ++d) {
    float qd = qs[pos][d];
#pragma unroll
    for (int i4 = 0; i4 < 4; ++i4) {
      float4 c4 = *(const float4*)&Cm[d][s * 16 + i4 * 4];
      o[i4 * 4 + 0] += qd * c4.x;
      o[i4 * 4 + 1] += qd * c4.y;
      o[i4 * 4 + 2] += qd * c4.z;
      o[i4 * 4 + 3] += qd * c4.w;
    }
  }
  u16* orow = att + (size_t)(batch * SEQ + u * 64 + pos) * DIM + head * DH + s * 16;
  uint4 pk0, pk1;
  pk0.x = (unsigned)f2b(o[0] * Dinv) | ((unsigned)f2b(o[1] * Dinv) << 16);
  pk0.y = (unsigned)f2b(o[2] * Dinv) | ((unsigned)f2b(o[3] * Dinv) << 16);
  pk0.z = (unsigned)f2b(o[4] * Dinv) | ((unsigned)f2b(o[5] * Dinv) << 16);
  pk0.w = (unsigned)f2b(o[6] * Dinv) | ((unsigned)f2b(o[7] * Dinv) << 16);
  pk1.x = (unsigned)f2b(o[8] * Dinv) | ((unsigned)f2b(o[9] * Dinv) << 16);
  pk1.y = (unsigned)f2b(o[10] * Dinv) | ((unsigned)f2b(o[11] * Dinv) << 16);
  pk1.z = (unsigned)f2b(o[12] * Dinv) | ((unsigned)f2b(o[13] * Dinv) << 16);
  pk1.w = (unsigned)f2b(o[14] * Dinv) | ((unsigned)f2b(o[15] * Dinv) << 16);
  *(uint4*)orow = pk0;
  *(uint4*)(orow + 8) = pk1;
}

// ---------------- host orchestration ----------------
extern "C" void kernel_launch(void* const* d_in, const int* in_sizes, int n_in,
                              void* d_out, int out_size, void* d_ws, size_t ws_size,
                              hipStream_t stream) {
  (void)in_sizes; (void)n_in; (void)out_size; (void)ws_size;
  const void* x_in = d_in[0];
  const void* ln1_g = d_in[1];
  const void* ln1_b = d_in[2];
  const void* wq = d_in[3];
  const void* wk = d_in[4];
  const void* wv = d_in[5];
  const void* wo = d_in[6];
  const void* bo = d_in[7];
  const void* ln2_g = d_in[8];
  const void* ln2_b = d_in[9];
  const void* w1 = d_in[10];
  const void* b1 = d_in[11];
  const void* w2 = d_in[12];
  const void* b2 = d_in[13];

  char* ws = (char*)d_ws;
  float* xf = (float*)(ws);              // 16 MiB f32 residual
  u16* h = (u16*)(ws + 16777216);        // 8 MiB bf16
  u16* region = (u16*)(ws + 25165824);   // 32 MiB: qkv (24 MiB) / gb (32 MiB)
  float* Ksum = (float*)(ws + 58720256); // 256 KiB
  float* KV = (float*)(ws + 58982400);   // 16 MiB
  u16* WR = (u16*)(ws + 75759616);       // 24 MiB repacked weights
  int* dt = (int*)(ws + 100925440);      // dtype flag
  u16* qkv = region;
  u16* gb = region;

  auto WqkvR = [&](int i) { return WR + (size_t)i * LSTRIDE + 0; };
  auto WoR   = [&](int i) { return WR + (size_t)i * LSTRIDE + 786432; };
  auto W1R   = [&](int i) { return WR + (size_t)i * LSTRIDE + 1048576; };
  auto W2R   = [&](int i) { return WR + (size_t)i * LSTRIDE + 2097152; };

  k_detect<<<dim3(1), dim3(1), 0, stream>>>(ln1_g, dt);

  const int nx = ROWS * DIM;
  k_x2f<<<dim3((nx + 255) / 256), dim3(256), 0, stream>>>(x_in, xf, nx, dt);

  k_repackQ<<<dim3(16, 8, 16), dim3(256), 0, stream>>>(wq, wk, wv, wo, WR, dt);
  k_repackF1<<<dim3(16, 32, 4), dim3(256), 0, stream>>>(w1, WR, dt);
  k_repackF2<<<dim3(64, 8, 4), dim3(256), 0, stream>>>(w2, WR, dt);

  for (int i = 0; i < 4; ++i) {
    // PreNorm(attn)
    k_ln<<<dim3(ROWS), dim3(256), 0, stream>>>(xf, ln1_g, ln1_b, (long)i * DIM, h, dt);
    // fused QKV gemm: [8192,512] @ [512,1536] — v4.4 pinned pipeline
    k_g8a<<<dim3(32, 6), dim3(512), 0, stream>>>(h, WqkvR(i), qkv, QKVW, DIM, dt);
    k_attnA<<<dim3(1024), dim3(256), 0, stream>>>(qkv, Ksum, KV);
    k_scan2<<<dim3(1024), dim3(64), 0, stream>>>(Ksum, KV);
    k_attnC<<<dim3(1024), dim3(256), 0, stream>>>(qkv, Ksum, KV, h);  // att -> h
    // x += att @ wo + bo  (N=512, BK=64 gemm3)
    k_gemm3<2, true, false, true, true><<<dim3(64, 8), dim3(256), 0, stream>>>(
        h, WoR(i), bo, (long)i * DIM, xf, xf, ROWS, DIM, DIM, dt);
    // PreNorm(FF)
    k_ln<<<dim3(ROWS), dim3(256), 0, stream>>>(xf, ln2_g, ln2_b, (long)i * DIM, h, dt);
    // FF up: [8192,512] @ [512,2048] + bias + gelu — v4.4 pinned pipeline
    k_g8b<<<dim3(32, 8), dim3(512), 0, stream>>>(h, W1R(i), b1, (long)i * FFDIM, gb, FFDIM, DIM, dt);
    // FF down: [8192,2048] @ [2048,512] + bias + residual (N=512, BK=64 gemm3)
    k_gemm3<2, true, false, true, true><<<dim3(64, 8), dim3(256), 0, stream>>>(
        gb, W2R(i), b2, (long)i * DIM, xf, xf, ROWS, DIM, FFDIM, dt);
  }

  k_store<<<dim3((nx + 255) / 256), dim3(256), 0, stream>>>(xf, d_out, nx, dt);
}

// Round 6
// 789.695 us; speedup vs baseline: 1.0828x; 1.0828x over previous
//
#include <hip/hip_runtime.h>

// ---------------- types / helpers ----------------
typedef unsigned short u16;
typedef __bf16 bf16x8 __attribute__((ext_vector_type(8)));
typedef float floatx4 __attribute__((ext_vector_type(4)));

#define DIM 512
#define HEADS 8
#define DH 64
#define SEQ 4096
#define BATCH 2
#define ROWS (BATCH * SEQ) /* 8192 */
#define FFDIM 2048
#define QKVW 1536 /* fused qkv row width */
#define LSTRIDE 3145728L /* repacked weight elems per layer */

#define SBAR0() __builtin_amdgcn_sched_barrier(0)
#define ASM_VMCNT(n) asm volatile("s_waitcnt vmcnt(" #n ")" ::: "memory")

__device__ __forceinline__ float b2f(u16 u) {
  union { float f; unsigned int i; } c; c.i = ((unsigned int)u) << 16; return c.f;
}
__device__ __forceinline__ u16 f2b(float f) {
  union { float f; unsigned int i; } c; c.f = f;
  unsigned int r = c.i + 0x7FFFu + ((c.i >> 16) & 1u);
  return (u16)(r >> 16);
}
__device__ __forceinline__ float ldin(const void* p, long i, int bf) {
  return bf ? b2f(((const u16*)p)[i]) : ((const float*)p)[i];
}
// async global->LDS, 16 bytes/lane. LDS dest = base + lane*16 (HW); global addr per-lane.
__device__ __forceinline__ void ld16(const u16* g, u16* l) {
  __builtin_amdgcn_global_load_lds((const __attribute__((address_space(1))) void*)g,
                                   (__attribute__((address_space(3))) void*)l, 16, 0, 0);
}
// unpack 8 u16 (as uint4) -> 8 floats
__device__ __forceinline__ void unpk8(uint4 p, float* o) {
  o[0] = b2f((u16)(p.x & 0xFFFF)); o[1] = b2f((u16)(p.x >> 16));
  o[2] = b2f((u16)(p.y & 0xFFFF)); o[3] = b2f((u16)(p.y >> 16));
  o[4] = b2f((u16)(p.z & 0xFFFF)); o[5] = b2f((u16)(p.z >> 16));
  o[6] = b2f((u16)(p.w & 0xFFFF)); o[7] = b2f((u16)(p.w >> 16));
}
// exact-enough GELU: erf via Abramowitz-Stegun 7.1.26 (|err| <= 1.5e-7) + fast exp.
__device__ __forceinline__ float fast_gelu(float v) {
  float z = fabsf(v) * 0.70710678118654752f;
  float t = 1.0f / (1.0f + 0.3275911f * z);
  float p = t * (0.254829592f +
           t * (-0.284496736f +
           t * (1.421413741f +
           t * (-1.453152027f +
           t * 1.061405429f))));
  float e = __expf(-z * z);
  float er = 1.0f - p * e;             // erf(|z|)
  float s = copysignf(er, v);          // erf(z)
  return 0.5f * v * (1.0f + s);
}

// ---------------- dtype detection ----------------
__global__ void k_detect(const void* __restrict__ g, int* __restrict__ flag) {
  *flag = (((const u16*)g)[0] == 0x3F80u) ? 1 : 0;
}

// ---------------- input x -> f32 / f32 -> out ----------------
__global__ __launch_bounds__(256) void k_x2f(const void* __restrict__ in, float* __restrict__ out,
                                             int n, const int* __restrict__ dt) {
  int bf = *dt;
  int i = blockIdx.x * 256 + threadIdx.x;
  if (i < n) out[i] = ldin(in, i, bf);
}
__global__ __launch_bounds__(256) void k_store(const float* __restrict__ in, void* __restrict__ out,
                                               int n, const int* __restrict__ dt) {
  int bf = *dt;
  int i = blockIdx.x * 256 + threadIdx.x;
  if (i < n) {
    if (bf) ((u16*)out)[i] = f2b(in[i]);
    else ((float*)out)[i] = in[i];
  }
}

// ---------------- weight repack (LDS-tiled, coalesced, batched) ----------------
__device__ __forceinline__ void repack_tile(const void* W, long w_off, u16* R, int N,
                                            int n16tot, int j_off, int kb, int jb, int bf) {
  int t = threadIdx.x;
  __shared__ float tile[32][65];
  int r0 = t >> 6;
  int c = t & 63;
#pragma unroll
  for (int i = 0; i < 8; ++i) {
    int rr = i * 4 + r0;
    tile[rr][c] = ldin(W, w_off + (long)(kb * 32 + rr) * N + jb * 64 + c, bf);
  }
  __syncthreads();
  int lane = t & 63, w = t >> 6;
  alignas(16) u16 tmp[8];
#pragma unroll
  for (int r = 0; r < 8; ++r) tmp[r] = f2b(tile[(lane >> 4) * 8 + r][w * 16 + (lane & 15)]);
  long oidx = (((long)kb * n16tot + j_off + jb * 4 + w) * 64 + lane) * 8;
  *(uint4*)(R + oidx) = *(const uint4*)tmp;
}
// all 512x512 weights: grid (16,8,16); z = layer*4 + type(0=q,1=k,2=v,3=o)
__global__ __launch_bounds__(256) void k_repackQ(const void* wq, const void* wk,
                                                 const void* wv, const void* wo,
                                                 u16* WR, const int* __restrict__ dt) {
  int bf = *dt;
  int z = blockIdx.z, layer = z >> 2, type = z & 3;
  const void* W = (type == 0) ? wq : (type == 1) ? wk : (type == 2) ? wv : wo;
  u16* R = WR + (long)layer * LSTRIDE + (type < 3 ? 0 : 786432);
  int n16tot = (type < 3) ? 96 : 32;
  int j_off = (type < 3) ? type * 32 : 0;
  repack_tile(W, (long)layer * 262144, R, 512, n16tot, j_off, blockIdx.x, blockIdx.y, bf);
}
// w1: grid (16,32,4)
__global__ __launch_bounds__(256) void k_repackF1(const void* w1, u16* WR, const int* __restrict__ dt) {
  int bf = *dt;
  repack_tile(w1, (long)blockIdx.z * 1048576, WR + (long)blockIdx.z * LSTRIDE + 1048576,
              2048, 128, 0, blockIdx.x, blockIdx.y, bf);
}
// w2: grid (64,8,4)
__global__ __launch_bounds__(256) void k_repackF2(const void* w2, u16* WR, const int* __restrict__ dt) {
  int bf = *dt;
  repack_tile(w2, (long)blockIdx.z * 1048576, WR + (long)blockIdx.z * LSTRIDE + 2097152,
              512, 32, 0, blockIdx.x, blockIdx.y, bf);
}

// ---------------- layernorm (f32 in, bf16 out) ----------------
__global__ __launch_bounds__(256) void k_ln(const float* __restrict__ x,
                                            const void* __restrict__ g, const void* __restrict__ b,
                                            long gb_off, u16* __restrict__ out,
                                            const int* __restrict__ dt) {
  int bf = *dt;
  int row = blockIdx.x;
  int t = threadIdx.x;
  const float* xr = x + (size_t)row * DIM;
  float v0 = xr[t], v1 = xr[t + 256];
  float s = v0 + v1;
  float s2 = v0 * v0 + v1 * v1;
#pragma unroll
  for (int off = 32; off > 0; off >>= 1) {
    s += __shfl_down(s, off);
    s2 += __shfl_down(s2, off);
  }
  __shared__ float red[8];
  int lane = t & 63, w = t >> 6;
  if (lane == 0) { red[w] = s; red[4 + w] = s2; }
  __syncthreads();
  float ts = red[0] + red[1] + red[2] + red[3];
  float ts2 = red[4] + red[5] + red[6] + red[7];
  float mean = ts * (1.0f / DIM);
  float var = ts2 * (1.0f / DIM) - mean * mean;
  float rstd = rsqrtf(var + 1e-5f);
  u16* orow = out + (size_t)row * DIM;
  orow[t] = f2b((v0 - mean) * rstd * ldin(g, gb_off + t, bf) + ldin(b, gb_off + t, bf));
  orow[t + 256] = f2b((v1 - mean) * rstd * ldin(g, gb_off + t + 256, bf) + ldin(b, gb_off + t + 256, bf));
}

// ---------------- MFMA GEMM v5 (N=512 GEMMs: WO, W2) ----------------
// Free-run pipeline: within a K-tile (BK=64) waves share no written LDS (reads hit the
// live buffer, stages target the idle buffer) -> ZERO intra-tile barriers. Sync per
// K-tile: barrier_A (reads done) -> stage(c+2)->live -> counted vmcnt (tile c+1 landed,
// c+2 stays in flight; never drain-0 in steady state) -> barrier_B (cross-wave landing).
// A-staging is coalesced (8 rows x 128B contiguous per inst) with st-XOR swizzle on the
// per-lane global source; swizzled ds_read is 2-way-conflict-free.
template <int NJ, bool HAS_BIAS, bool DO_GELU, bool HAS_RES, bool OUT_F32>
__global__ __launch_bounds__(256) void k_gemm3(const u16* __restrict__ A, const u16* __restrict__ BR,
                                               const void* bias, long bias_off,
                                               const float* res, void* outp,
                                               int M, int N, int K, const int* dtflag) {
  int lane = threadIdx.x & 63;
  int wid = threadIdx.x >> 6;
  int wm = wid & 1, wn = wid >> 1;
  int m0 = blockIdx.x * 128;
  int n0 = blockIdx.y * (NJ * 32);
  int n16 = N >> 4;
  int n016 = n0 >> 4;

  constexpr int BUFB = (16 + 4 * NJ) * 1024;  // A 16KB + B NJ*4KB per buffer (bytes)
  __shared__ alignas(16) char smem[2 * BUFB];

  floatx4 acc[4][NJ];
#pragma unroll
  for (int mi = 0; mi < 4; ++mi)
#pragma unroll
    for (int j = 0; j < NJ; ++j)
#pragma unroll
      for (int r = 0; r < 4; ++r) acc[mi][j][r] = 0.0f;

  // A staging: coalesced 8-row x 128B insts, pre-swizzled source (rule #21 pattern)
  int arow = lane >> 3;                  // row within 8-row inst group
  int acu = ((lane & 7) ^ arow) * 8;     // pre-swizzled col (u16)
  const u16* AgS = A + (size_t)(m0 + wid * 32 + arow) * K + acu;
  int nKB = K >> 6;

  auto stage = [&](int kb, int b) {
    u16* aL = (u16*)(smem + b * BUFB);
    u16* bL = aL + 8192;
#pragma unroll
    for (int j = 0; j < 4; ++j)   // 16 groups of 8 rows; wave wid owns groups wid*4..+3
      ld16(AgS + (size_t)(j * 8) * K + (size_t)kb * 64, aL + (wid * 4 + j) * 512);
#pragma unroll
    for (int sj = 0; sj < NJ / 2; ++sj) {
      int jg = wid * (NJ / 2) + sj;
      ld16(BR + (((size_t)(kb * 2) * n16 + n016 + jg) * 64 + lane) * 8, bL + jg * 512);
      ld16(BR + (((size_t)(kb * 2 + 1) * n16 + n016 + jg) * 64 + lane) * 8,
           bL + NJ * 1024 + jg * 512);
    }
  };

  // swizzled A-read offsets (u16)
  int aoff = (lane & 15) * 64;
  int axor = (lane & 7) << 3;
  int ak0 = ((lane >> 4) * 8) ^ axor;
  int ak1 = (32 + (lane >> 4) * 8) ^ axor;

  // prologue: tiles 0 and 1 staged; tile 0 must land (NJ loads + 4 A per stage in flight)
  stage(0, 0);
  stage(1, 1);
  if constexpr (NJ == 2) ASM_VMCNT(6); else ASM_VMCNT(8);
  __builtin_amdgcn_s_barrier();
  SBAR0();

  for (int kb = 0; kb < nKB; ++kb) {
    const u16* aL = (const u16*)(smem + (kb & 1) * BUFB);
    const u16* bL = aL + 8192;
    // free-run compute over the whole K-tile (no barriers; compiler schedules lgkmcnt)
#pragma unroll
    for (int h = 0; h < 2; ++h) {
      int akh = h ? ak1 : ak0;
      bf16x8 afr[4], bfr[NJ];
#pragma unroll
      for (int mi = 0; mi < 4; ++mi)
        afr[mi] = *(const bf16x8*)(aL + (wm * 4 + mi) * 1024 + aoff + akh);
#pragma unroll
      for (int j = 0; j < NJ; ++j)
        bfr[j] = *(const bf16x8*)(bL + h * NJ * 1024 + ((wn * NJ + j) * 64 + lane) * 8);
      __builtin_amdgcn_s_setprio(1);
#pragma unroll
      for (int mi = 0; mi < 4; ++mi)
#pragma unroll
        for (int j = 0; j < NJ; ++j)
          acc[mi][j] = __builtin_amdgcn_mfma_f32_16x16x32_bf16(afr[mi], bfr[j], acc[mi][j], 0, 0, 0);
      __builtin_amdgcn_s_setprio(0);
    }
    SBAR0();
    __builtin_amdgcn_s_barrier();        // A: all waves done reading live buf
    if (kb + 2 < nKB) {
      stage(kb + 2, kb & 1);             // restage live buf (safe now)
      if constexpr (NJ == 2) ASM_VMCNT(6); else ASM_VMCNT(8);  // tile kb+1 landed
    } else if (kb + 1 < nKB) {
      ASM_VMCNT(0);                      // tail: tile kb+1 landed
    }
    __builtin_amdgcn_s_barrier();        // B: landing is cross-wave
    SBAR0();
  }

  // ---- epilogue: per-wave LDS transpose -> coalesced vector stores ----
  __syncthreads();
  constexpr int EPS = 84;
  float* ep = (float*)smem + wid * (16 * EPS);
  constexpr int C = NJ * 16;
  int dtv = HAS_BIAS ? *dtflag : 0;
  int nW = n0 + wn * C;
  int mWbase = m0 + wm * 64;

#pragma unroll
  for (int mi = 0; mi < 4; ++mi) {
#pragma unroll
    for (int j = 0; j < NJ; ++j) {
      float bv = HAS_BIAS ? ldin(bias, bias_off + nW + j * 16 + (lane & 15), dtv) : 0.0f;
#pragma unroll
      for (int r = 0; r < 4; ++r) {
        float v = acc[mi][j][r] + bv;
        if (DO_GELU) v = fast_gelu(v);
        ep[((lane >> 4) * 4 + r) * EPS + j * 16 + (lane & 15)] = v;
      }
    }
    __builtin_amdgcn_s_waitcnt(0);
    if (OUT_F32) {
      constexpr int LPR = C / 4;
      constexpr int RPP = 64 / LPR;
      constexpr int NP = 16 / RPP;
#pragma unroll
      for (int p = 0; p < NP; ++p) {
        int row = p * RPP + lane / LPR;
        int cb = (lane % LPR) * 4;
        float4 v = *(const float4*)&ep[row * EPS + cb];
        size_t gi = (size_t)(mWbase + mi * 16 + row) * N + nW + cb;
        if (HAS_RES) {
          float4 rv = *(const float4*)&res[gi];
          v.x += rv.x; v.y += rv.y; v.z += rv.z; v.w += rv.w;
        }
        *(float4*)&((float*)outp)[gi] = v;
      }
    } else {
      constexpr int LPR = C / 8;
      constexpr int RPP = 64 / LPR;
      constexpr int NP = 16 / RPP;
#pragma unroll
      for (int p = 0; p < NP; ++p) {
        int row = p * RPP + lane / LPR;
        int cb = (lane % LPR) * 8;
        const float* er = &ep[row * EPS + cb];
        uint4 pk;
        pk.x = (unsigned)f2b(er[0]) | ((unsigned)f2b(er[1]) << 16);
        pk.y = (unsigned)f2b(er[2]) | ((unsigned)f2b(er[3]) << 16);
        pk.z = (unsigned)f2b(er[4]) | ((unsigned)f2b(er[5]) << 16);
        pk.w = (unsigned)f2b(er[6]) | ((unsigned)f2b(er[7]) << 16);
        size_t gi = (size_t)(mWbase + mi * 16 + row) * N + nW + cb;
        *(uint4*)&((u16*)outp)[gi] = pk;
      }
    }
    __builtin_amdgcn_s_waitcnt(0);
  }
}

// ---------------- MFMA GEMM v5: 256x256 free-run pipeline (QKV, W1) ----------------
// Same free-run sync as k_gemm3 v5; geometry as v4.3 (8 waves 2m x 4n, BK=64,
// coalesced swizzled A-staging, fragment-order B). 8 loads/wave per K-tile stage.
template <bool HAS_BIAS, bool DO_GELU>
__device__ __forceinline__ void gemm8_body(const u16* __restrict__ A, const u16* __restrict__ BR,
                                           const void* bias, long bias_off,
                                           u16* __restrict__ outp,
                                           int N, int K, const int* dtflag) {
  int lane = threadIdx.x & 63;
  int w = threadIdx.x >> 6;       // wave 0..7
  int wm = w >> 2, wn = w & 3;    // 2 x 4
  int m0 = blockIdx.x * 256;
  int n0 = blockIdx.y * 256;
  int n16 = N >> 4;
  int n016 = n0 >> 4;
  int NKT = K >> 6;               // K-tiles of 64 (assumes K >= 128)

  __shared__ alignas(16) u16 smem8[65536];  // 2 bufs x (A 32KB | B 32KB) = 128 KiB

  int arow = lane >> 3;
  int acu = ((lane & 7) ^ arow) * 8;
  const u16* Ag0 = A + (size_t)(m0 + (w * 2 + 0) * 8 + arow) * K + acu;
  const u16* Ag1 = A + (size_t)(m0 + (w * 2 + 1) * 8 + arow) * K + acu;
  const u16* Bg = BR + (size_t)n016 * 512 + lane * 8;

  // stage whole K-tile kt into dbuf: A 4 insts + B 4 insts per wave = 8 loads
  auto stage_full = [&](int kt, int dbuf) {
    u16* aD = smem8 + dbuf * 32768;
    u16* bD = aD + 16384;
    size_t go = (size_t)kt * 64;
#pragma unroll
    for (int half = 0; half < 2; ++half) {
      ld16(Ag0 + (size_t)half * 128 * K + go, aD + half * 8192 + (w * 2 + 0) * 512);
      ld16(Ag1 + (size_t)half * 128 * K + go, aD + half * 8192 + (w * 2 + 1) * 512);
    }
#pragma unroll
    for (int kk = 0; kk < 2; ++kk) {
      const u16* s = Bg + ((size_t)(kt * 2 + kk) * n16) * 512;
      ld16(s + (size_t)w * 512,       bD + kk * 8192 + (0 + w) * 512);
      ld16(s + (size_t)(8 + w) * 512, bD + kk * 8192 + (8 + w) * 512);
    }
  };

  int aoff = (lane & 15) * 64;
  int axor = (lane & 7) << 3;
  int ak0 = ((lane >> 4) * 8) ^ axor;
  int ak1 = (32 + (lane >> 4) * 8) ^ axor;

  floatx4 acc[8][4];
#pragma unroll
  for (int mi = 0; mi < 8; ++mi)
#pragma unroll
    for (int j = 0; j < 4; ++j)
#pragma unroll
      for (int r = 0; r < 4; ++r) acc[mi][j][r] = 0.0f;

  // prologue: tiles 0 and 1 staged; tile 0 must land (8 tile-1 loads in flight)
  stage_full(0, 0);
  stage_full(1, 1);
  ASM_VMCNT(8);
  __builtin_amdgcn_s_barrier();
  SBAR0();

  for (int c = 0; c < NKT; ++c) {
    const u16* aL = smem8 + (c & 1) * 32768;
    const u16* bL = aL + 16384;
    // ---- free-run compute: whole K-tile, no barriers ----
#pragma unroll
    for (int kk = 0; kk < 2; ++kk) {
      int akh = kk ? ak1 : ak0;
      bf16x8 bfr[4];
#pragma unroll
      for (int i = 0; i < 4; ++i)
        bfr[i] = *(const bf16x8*)(bL + ((kk * 16 + wn * 4 + i) * 64 + lane) * 8);
#pragma unroll
      for (int mh = 0; mh < 2; ++mh) {
        bf16x8 afr[4];
#pragma unroll
        for (int i = 0; i < 4; ++i)
          afr[i] = *(const bf16x8*)(aL + (wm * 8 + mh * 4 + i) * 1024 + aoff + akh);
        __builtin_amdgcn_s_setprio(1);
#pragma unroll
        for (int mi = 0; mi < 4; ++mi)
#pragma unroll
          for (int j = 0; j < 4; ++j)
            acc[mh * 4 + mi][j] =
                __builtin_amdgcn_mfma_f32_16x16x32_bf16(afr[mi], bfr[j], acc[mh * 4 + mi][j], 0, 0, 0);
        __builtin_amdgcn_s_setprio(0);
      }
    }
    SBAR0();
    __builtin_amdgcn_s_barrier();        // A: all waves done reading live buf
    if (c + 2 < NKT) {
      stage_full(c + 2, c & 1);          // restage live buf
      ASM_VMCNT(8);                      // tile c+1 landed; c+2 stays in flight
    } else if (c + 1 < NKT) {
      ASM_VMCNT(0);
    }
    __builtin_amdgcn_s_barrier();        // B: landing cross-wave
    SBAR0();
  }

  ASM_VMCNT(0);
  __builtin_amdgcn_s_barrier();

  // ---- epilogue: per-wave LDS transpose -> coalesced bf16 stores ----
  constexpr int EPS = 68;
  float* ep = (float*)smem8 + w * (16 * EPS);
  int dtv = HAS_BIAS ? *dtflag : 0;
  int nW = n0 + wn * 64;
  int mW = m0 + wm * 128;

#pragma unroll
  for (int mf = 0; mf < 8; ++mf) {
#pragma unroll
    for (int j = 0; j < 4; ++j) {
      float bv = HAS_BIAS ? ldin(bias, bias_off + nW + j * 16 + (lane & 15), dtv) : 0.0f;
#pragma unroll
      for (int r = 0; r < 4; ++r) {
        float v = acc[mf][j][r] + bv;
        if (DO_GELU) v = fast_gelu(v);
        ep[((lane >> 4) * 4 + r) * EPS + j * 16 + (lane & 15)] = v;
      }
    }
    asm volatile("s_waitcnt lgkmcnt(0)" ::: "memory");
#pragma unroll
    for (int p = 0; p < 2; ++p) {
      int row = p * 8 + (lane >> 3);
      int cb = (lane & 7) * 8;
      const float* er = &ep[row * EPS + cb];
      uint4 pk;
      pk.x = (unsigned)f2b(er[0]) | ((unsigned)f2b(er[1]) << 16);
      pk.y = (unsigned)f2b(er[2]) | ((unsigned)f2b(er[3]) << 16);
      pk.z = (unsigned)f2b(er[4]) | ((unsigned)f2b(er[5]) << 16);
      pk.w = (unsigned)f2b(er[6]) | ((unsigned)f2b(er[7]) << 16);
      size_t gi = (size_t)(mW + mf * 16 + row) * N + nW + cb;
      *(uint4*)&outp[gi] = pk;
    }
    asm volatile("s_waitcnt lgkmcnt(0)" ::: "memory");
  }
}

// separately-named instantiations (independent codegen, distinct profile rows)
__global__ __launch_bounds__(512, 2) void k_g8a(const u16* __restrict__ A, const u16* __restrict__ BR,
                                                u16* __restrict__ outp, int N, int K,
                                                const int* dtflag) {
  gemm8_body<false, false>(A, BR, nullptr, 0, outp, N, K, dtflag);
}
__global__ __launch_bounds__(512, 2) void k_g8b(const u16* __restrict__ A, const u16* __restrict__ BR,
                                                const void* bias, long bias_off,
                                                u16* __restrict__ outp, int N, int K,
                                                const int* dtflag) {
  gemm8_body<true, true>(A, BR, bias, bias_off, outp, N, K, dtflag);
}

// ---------------- attention phase A: per-bucket exp(k)^T v and key sums ----------------
__global__ __launch_bounds__(256) void k_attnA(const u16* __restrict__ qkv,
                                               float* __restrict__ Ksum, float* __restrict__ KV) {
  int u = blockIdx.x & 63;
  int bh = blockIdx.x >> 6;
  int head = bh & 7, batch = bh >> 3;
  int t = threadIdx.x;
  int pr = t >> 2, s = t & 3;
  __shared__ float kex[64][68];
  __shared__ float vv[64][68];
  const u16* base = qkv + (size_t)(batch * SEQ + u * 64 + pr) * QKVW + head * DH;
  uint4 kp0 = *(const uint4*)(base + 512 + s * 16);
  uint4 kp1 = *(const uint4*)(base + 512 + s * 16 + 8);
  uint4 vp0 = *(const uint4*)(base + 1024 + s * 16);
  uint4 vp1 = *(const uint4*)(base + 1024 + s * 16 + 8);
  float kf[16], vf[16];
  unpk8(kp0, kf); unpk8(kp1, kf + 8);
  unpk8(vp0, vf); unpk8(vp1, vf + 8);
#pragma unroll
  for (int i = 0; i < 16; ++i) {
    kex[pr][s * 16 + i] = expf(fminf(kf[i], 30.0f));
    vv[pr][s * 16 + i] = vf[i];
  }
  __syncthreads();
  int d = pr;
  float acc[16];
#pragma unroll
  for (int i = 0; i < 16; ++i) acc[i] = 0.0f;
  float ks = 0.0f;
  for (int p = 0; p < 64; ++p) {
    float kp = kex[p][d];
    ks += kp;
#pragma unroll
    for (int i4 = 0; i4 < 4; ++i4) {
      float4 v4 = *(const float4*)&vv[p][s * 16 + i4 * 4];
      acc[i4 * 4 + 0] += kp * v4.x;
      acc[i4 * 4 + 1] += kp * v4.y;
      acc[i4 * 4 + 2] += kp * v4.z;
      acc[i4 * 4 + 3] += kp * v4.w;
    }
  }
  float* kvout = KV + (size_t)blockIdx.x * 4096 + d * 64 + s * 16;
#pragma unroll
  for (int i4 = 0; i4 < 4; ++i4) {
    float4 o; o.x = acc[i4 * 4]; o.y = acc[i4 * 4 + 1]; o.z = acc[i4 * 4 + 2]; o.w = acc[i4 * 4 + 3];
    *(float4*)(kvout + i4 * 4) = o;
  }
  if (s == 0) Ksum[(size_t)blockIdx.x * 64 + d] = ks;
}

// ---------------- attention phase B: exclusive prefix over buckets ----------------
__global__ __launch_bounds__(64) void k_scan2(float* __restrict__ Ksum, float* __restrict__ KV) {
  int bh = blockIdx.x >> 6;
  int d = blockIdx.x & 63;
  int e = threadIdx.x;
  float* p0 = KV + (size_t)bh * 64 * 4096 + d * 64 + e;
  float v[64];
#pragma unroll
  for (int u = 0; u < 64; ++u) v[u] = p0[(size_t)u * 4096];
  float run = 0.0f;
#pragma unroll
  for (int u = 0; u < 64; ++u) { float c = v[u]; v[u] = run; run += c; }
#pragma unroll
  for (int u = 0; u < 64; ++u) p0[(size_t)u * 4096] = v[u];
  if (d == 0) {
    float* kp = Ksum + (size_t)bh * 4096 + e;
    float sv[64];
#pragma unroll
    for (int u = 0; u < 64; ++u) sv[u] = kp[u * 64];
    float r = 0.0f;
#pragma unroll
    for (int u = 0; u < 64; ++u) { float c = sv[u]; sv[u] = r; r += c; }
#pragma unroll
    for (int u = 0; u < 64; ++u) kp[u * 64] = sv[u];
  }
}

// ---------------- attention phase C: softmax(q), D, output ----------------
__global__ __launch_bounds__(256) void k_attnC(const u16* __restrict__ qkv, const float* __restrict__ Ksum,
                                               const float* __restrict__ KV, u16* __restrict__ att) {
  int u = blockIdx.x & 63;
  int bh = blockIdx.x >> 6;
  int head = bh & 7, batch = bh >> 3;
  int t = threadIdx.x;
  int pos = t >> 2, s = t & 3;
  __shared__ float Cm[64][68];
  __shared__ float qs[64][68];
  __shared__ float S[64];
  const float* kvb = KV + (size_t)blockIdx.x * 4096 + pos * 64 + s * 16;
#pragma unroll
  for (int i4 = 0; i4 < 4; ++i4)
    *(float4*)&Cm[pos][s * 16 + i4 * 4] = *(const float4*)(kvb + i4 * 4);
  if (t < 64) S[t] = Ksum[(size_t)blockIdx.x * 64 + t];
  size_t grow = (size_t)(batch * SEQ + u * 64 + pos) * QKVW + head * DH;
  uint4 q0 = *(const uint4*)(qkv + grow + s * 16);
  uint4 q1 = *(const uint4*)(qkv + grow + s * 16 + 8);
  float q[16];
  unpk8(q0, q); unpk8(q1, q + 8);
  float mx = q[0];
#pragma unroll
  for (int i = 1; i < 16; ++i) mx = fmaxf(mx, q[i]);
  mx = fmaxf(mx, __shfl_xor(mx, 1));
  mx = fmaxf(mx, __shfl_xor(mx, 2));
  float sum = 0.0f;
#pragma unroll
  for (int i = 0; i < 16; ++i) { q[i] = expf(q[i] - mx); sum += q[i]; }
  sum += __shfl_xor(sum, 1);
  sum += __shfl_xor(sum, 2);
  float scale = 0.125f / sum;  // * e^-0.5 with e=64
  __syncthreads();  // S ready
  float Dp = 0.0f;
#pragma unroll
  for (int i = 0; i < 16; ++i) { q[i] *= scale; Dp += q[i] * S[s * 16 + i]; }
  Dp += __shfl_xor(Dp, 1);
  Dp += __shfl_xor(Dp, 2);
  float Dinv = 1.0f / fmaxf(Dp, 1e-3f);
#pragma unroll
  for (int i = 0; i < 16; ++i) qs[pos][s * 16 + i] = q[i];
  __syncthreads();  // Cm + qs ready
  float o[16];
#pragma unroll
  for (int i = 0; i < 16; ++i) o[i] = 0.0f;
  for (int d = 0; d < 64; ++d) {
    float qd = qs[pos][d];
#pragma unroll
    for (int i4 = 0; i4 < 4; ++i4) {
      float4 c4 = *(const float4*)&Cm[d][s * 16 + i4 * 4];
      o[i4 * 4 + 0] += qd * c4.x;
      o[i4 * 4 + 1] += qd * c4.y;
      o[i4 * 4 + 2] += qd * c4.z;
      o[i4 * 4 + 3] += qd * c4.w;
    }
  }
  u16* orow = att + (size_t)(batch * SEQ + u * 64 + pos) * DIM + head * DH + s * 16;
  uint4 pk0, pk1;
  pk0.x = (unsigned)f2b(o[0] * Dinv) | ((unsigned)f2b(o[1] * Dinv) << 16);
  pk0.y = (unsigned)f2b(o[2] * Dinv) | ((unsigned)f2b(o[3] * Dinv) << 16);
  pk0.z = (unsigned)f2b(o[4] * Dinv) | ((unsigned)f2b(o[5] * Dinv) << 16);
  pk0.w = (unsigned)f2b(o[6] * Dinv) | ((unsigned)f2b(o[7] * Dinv) << 16);
  pk1.x = (unsigned)f2b(o[8] * Dinv) | ((unsigned)f2b(o[9] * Dinv) << 16);
  pk1.y = (unsigned)f2b(o[10] * Dinv) | ((unsigned)f2b(o[11] * Dinv) << 16);
  pk1.z = (unsigned)f2b(o[12] * Dinv) | ((unsigned)f2b(o[13] * Dinv) << 16);
  pk1.w = (unsigned)f2b(o[14] * Dinv) | ((unsigned)f2b(o[15] * Dinv) << 16);
  *(uint4*)orow = pk0;
  *(uint4*)(orow + 8) = pk1;
}

// ---------------- host orchestration ----------------
extern "C" void kernel_launch(void* const* d_in, const int* in_sizes, int n_in,
                              void* d_out, int out_size, void* d_ws, size_t ws_size,
                              hipStream_t stream) {
  (void)in_sizes; (void)n_in; (void)out_size; (void)ws_size;
  const void* x_in = d_in[0];
  const void* ln1_g = d_in[1];
  const void* ln1_b = d_in[2];
  const void* wq = d_in[3];
  const void* wk = d_in[4];
  const void* wv = d_in[5];
  const void* wo = d_in[6];
  const void* bo = d_in[7];
  const void* ln2_g = d_in[8];
  const void* ln2_b = d_in[9];
  const void* w1 = d_in[10];
  const void* b1 = d_in[11];
  const void* w2 = d_in[12];
  const void* b2 = d_in[13];

  char* ws = (char*)d_ws;
  float* xf = (float*)(ws);              // 16 MiB f32 residual
  u16* h = (u16*)(ws + 16777216);        // 8 MiB bf16
  u16* region = (u16*)(ws + 25165824);   // 32 MiB: qkv (24 MiB) / gb (32 MiB)
  float* Ksum = (float*)(ws + 58720256); // 256 KiB
  float* KV = (float*)(ws + 58982400);   // 16 MiB
  u16* WR = (u16*)(ws + 75759616);       // 24 MiB repacked weights
  int* dt = (int*)(ws + 100925440);      // dtype flag
  u16* qkv = region;
  u16* gb = region;

  auto WqkvR = [&](int i) { return WR + (size_t)i * LSTRIDE + 0; };
  auto WoR   = [&](int i) { return WR + (size_t)i * LSTRIDE + 786432; };
  auto W1R   = [&](int i) { return WR + (size_t)i * LSTRIDE + 1048576; };
  auto W2R   = [&](int i) { return WR + (size_t)i * LSTRIDE + 2097152; };

  k_detect<<<dim3(1), dim3(1), 0, stream>>>(ln1_g, dt);

  const int nx = ROWS * DIM;
  k_x2f<<<dim3((nx + 255) / 256), dim3(256), 0, stream>>>(x_in, xf, nx, dt);

  k_repackQ<<<dim3(16, 8, 16), dim3(256), 0, stream>>>(wq, wk, wv, wo, WR, dt);
  k_repackF1<<<dim3(16, 32, 4), dim3(256), 0, stream>>>(w1, WR, dt);
  k_repackF2<<<dim3(64, 8, 4), dim3(256), 0, stream>>>(w2, WR, dt);

  for (int i = 0; i < 4; ++i) {
    // PreNorm(attn)
    k_ln<<<dim3(ROWS), dim3(256), 0, stream>>>(xf, ln1_g, ln1_b, (long)i * DIM, h, dt);
    // fused QKV gemm: [8192,512] @ [512,1536] — free-run 256x256 pipeline
    k_g8a<<<dim3(32, 6), dim3(512), 0, stream>>>(h, WqkvR(i), qkv, QKVW, DIM, dt);
    k_attnA<<<dim3(1024), dim3(256), 0, stream>>>(qkv, Ksum, KV);
    k_scan2<<<dim3(1024), dim3(64), 0, stream>>>(Ksum, KV);
    k_attnC<<<dim3(1024), dim3(256), 0, stream>>>(qkv, Ksum, KV, h);  // att -> h
    // x += att @ wo + bo  (N=512, free-run k_gemm3)
    k_gemm3<2, true, false, true, true><<<dim3(64, 8), dim3(256), 0, stream>>>(
        h, WoR(i), bo, (long)i * DIM, xf, xf, ROWS, DIM, DIM, dt);
    // PreNorm(FF)
    k_ln<<<dim3(ROWS), dim3(256), 0, stream>>>(xf, ln2_g, ln2_b, (long)i * DIM, h, dt);
    // FF up: [8192,512] @ [512,2048] + bias + gelu — free-run 256x256 pipeline
    k_g8b<<<dim3(32, 8), dim3(512), 0, stream>>>(h, W1R(i), b1, (long)i * FFDIM, gb, FFDIM, DIM, dt);
    // FF down: [8192,2048] @ [2048,512] + bias + residual (N=512, free-run k_gemm3)
    k_gemm3<2, true, false, true, true><<<dim3(64, 8), dim3(256), 0, stream>>>(
        gb, W2R(i), b2, (long)i * DIM, xf, xf, ROWS, DIM, FFDIM, dt);
  }

  k_store<<<dim3((nx + 255) / 256), dim3(256), 0, stream>>>(xf, d_out, nx, dt);
}

// Round 7
// 761.611 us; speedup vs baseline: 1.1227x; 1.0369x over previous
//
#include <hip/hip_runtime.h>

// ---------------- types / helpers ----------------
typedef unsigned short u16;
typedef __bf16 bf16x8 __attribute__((ext_vector_type(8)));
typedef float floatx4 __attribute__((ext_vector_type(4)));

#define DIM 512
#define HEADS 8
#define DH 64
#define SEQ 4096
#define BATCH 2
#define ROWS (BATCH * SEQ) /* 8192 */
#define FFDIM 2048
#define QKVW 1536 /* fused qkv row width */
#define LSTRIDE 3145728L /* repacked weight elems per layer */
#define GK 512   /* K of all gemm8 GEMMs (QKV, W1) */

#define SBAR0() __builtin_amdgcn_sched_barrier(0)
#define ASM_VMCNT(n) asm volatile("s_waitcnt vmcnt(" #n ")" ::: "memory")

__device__ __forceinline__ float b2f(u16 u) {
  union { float f; unsigned int i; } c; c.i = ((unsigned int)u) << 16; return c.f;
}
__device__ __forceinline__ u16 f2b(float f) {
  union { float f; unsigned int i; } c; c.f = f;
  unsigned int r = c.i + 0x7FFFu + ((c.i >> 16) & 1u);
  return (u16)(r >> 16);
}
__device__ __forceinline__ float ldin(const void* p, long i, int bf) {
  return bf ? b2f(((const u16*)p)[i]) : ((const float*)p)[i];
}
// async global->LDS, 16 bytes/lane. LDS dest = base + lane*16 (HW); global addr per-lane.
__device__ __forceinline__ void ld16(const u16* g, u16* l) {
  __builtin_amdgcn_global_load_lds((const __attribute__((address_space(1))) void*)g,
                                   (__attribute__((address_space(3))) void*)l, 16, 0, 0);
}
// unpack 8 u16 (as uint4) -> 8 floats
__device__ __forceinline__ void unpk8(uint4 p, float* o) {
  o[0] = b2f((u16)(p.x & 0xFFFF)); o[1] = b2f((u16)(p.x >> 16));
  o[2] = b2f((u16)(p.y & 0xFFFF)); o[3] = b2f((u16)(p.y >> 16));
  o[4] = b2f((u16)(p.z & 0xFFFF)); o[5] = b2f((u16)(p.z >> 16));
  o[6] = b2f((u16)(p.w & 0xFFFF)); o[7] = b2f((u16)(p.w >> 16));
}
// exact-enough GELU: erf via Abramowitz-Stegun 7.1.26 (|err| <= 1.5e-7) + fast exp.
__device__ __forceinline__ float fast_gelu(float v) {
  float z = fabsf(v) * 0.70710678118654752f;
  float t = 1.0f / (1.0f + 0.3275911f * z);
  float p = t * (0.254829592f +
           t * (-0.284496736f +
           t * (1.421413741f +
           t * (-1.453152027f +
           t * 1.061405429f))));
  float e = __expf(-z * z);
  float er = 1.0f - p * e;             // erf(|z|)
  float s = copysignf(er, v);          // erf(z)
  return 0.5f * v * (1.0f + s);
}

// ---------------- dtype detection ----------------
__global__ void k_detect(const void* __restrict__ g, int* __restrict__ flag) {
  *flag = (((const u16*)g)[0] == 0x3F80u) ? 1 : 0;
}

// ---------------- input x -> f32 / f32 -> out ----------------
__global__ __launch_bounds__(256) void k_x2f(const void* __restrict__ in, float* __restrict__ out,
                                             int n, const int* __restrict__ dt) {
  int bf = *dt;
  int i = blockIdx.x * 256 + threadIdx.x;
  if (i < n) out[i] = ldin(in, i, bf);
}
__global__ __launch_bounds__(256) void k_store(const float* __restrict__ in, void* __restrict__ out,
                                               int n, const int* __restrict__ dt) {
  int bf = *dt;
  int i = blockIdx.x * 256 + threadIdx.x;
  if (i < n) {
    if (bf) ((u16*)out)[i] = f2b(in[i]);
    else ((float*)out)[i] = in[i];
  }
}

// ---------------- weight repack (LDS-tiled, coalesced, batched) ----------------
__device__ __forceinline__ void repack_tile(const void* W, long w_off, u16* R, int N,
                                            int n16tot, int j_off, int kb, int jb, int bf) {
  int t = threadIdx.x;
  __shared__ float tile[32][65];
  int r0 = t >> 6;
  int c = t & 63;
#pragma unroll
  for (int i = 0; i < 8; ++i) {
    int rr = i * 4 + r0;
    tile[rr][c] = ldin(W, w_off + (long)(kb * 32 + rr) * N + jb * 64 + c, bf);
  }
  __syncthreads();
  int lane = t & 63, w = t >> 6;
  alignas(16) u16 tmp[8];
#pragma unroll
  for (int r = 0; r < 8; ++r) tmp[r] = f2b(tile[(lane >> 4) * 8 + r][w * 16 + (lane & 15)]);
  long oidx = (((long)kb * n16tot + j_off + jb * 4 + w) * 64 + lane) * 8;
  *(uint4*)(R + oidx) = *(const uint4*)tmp;
}
// all 512x512 weights: grid (16,8,16); z = layer*4 + type(0=q,1=k,2=v,3=o)
__global__ __launch_bounds__(256) void k_repackQ(const void* wq, const void* wk,
                                                 const void* wv, const void* wo,
                                                 u16* WR, const int* __restrict__ dt) {
  int bf = *dt;
  int z = blockIdx.z, layer = z >> 2, type = z & 3;
  const void* W = (type == 0) ? wq : (type == 1) ? wk : (type == 2) ? wv : wo;
  u16* R = WR + (long)layer * LSTRIDE + (type < 3 ? 0 : 786432);
  int n16tot = (type < 3) ? 96 : 32;
  int j_off = (type < 3) ? type * 32 : 0;
  repack_tile(W, (long)layer * 262144, R, 512, n16tot, j_off, blockIdx.x, blockIdx.y, bf);
}
// w1: grid (16,32,4)
__global__ __launch_bounds__(256) void k_repackF1(const void* w1, u16* WR, const int* __restrict__ dt) {
  int bf = *dt;
  repack_tile(w1, (long)blockIdx.z * 1048576, WR + (long)blockIdx.z * LSTRIDE + 1048576,
              2048, 128, 0, blockIdx.x, blockIdx.y, bf);
}
// w2: grid (64,8,4)
__global__ __launch_bounds__(256) void k_repackF2(const void* w2, u16* WR, const int* __restrict__ dt) {
  int bf = *dt;
  repack_tile(w2, (long)blockIdx.z * 1048576, WR + (long)blockIdx.z * LSTRIDE + 2097152,
              512, 32, 0, blockIdx.x, blockIdx.y, bf);
}

// ---------------- layernorm (f32 in, bf16 out) ----------------
__global__ __launch_bounds__(256) void k_ln(const float* __restrict__ x,
                                            const void* __restrict__ g, const void* __restrict__ b,
                                            long gb_off, u16* __restrict__ out,
                                            const int* __restrict__ dt) {
  int bf = *dt;
  int row = blockIdx.x;
  int t = threadIdx.x;
  const float* xr = x + (size_t)row * DIM;
  float v0 = xr[t], v1 = xr[t + 256];
  float s = v0 + v1;
  float s2 = v0 * v0 + v1 * v1;
#pragma unroll
  for (int off = 32; off > 0; off >>= 1) {
    s += __shfl_down(s, off);
    s2 += __shfl_down(s2, off);
  }
  __shared__ float red[8];
  int lane = t & 63, w = t >> 6;
  if (lane == 0) { red[w] = s; red[4 + w] = s2; }
  __syncthreads();
  float ts = red[0] + red[1] + red[2] + red[3];
  float ts2 = red[4] + red[5] + red[6] + red[7];
  float mean = ts * (1.0f / DIM);
  float var = ts2 * (1.0f / DIM) - mean * mean;
  float rstd = rsqrtf(var + 1e-5f);
  u16* orow = out + (size_t)row * DIM;
  orow[t] = f2b((v0 - mean) * rstd * ldin(g, gb_off + t, bf) + ldin(b, gb_off + t, bf));
  orow[t + 256] = f2b((v1 - mean) * rstd * ldin(g, gb_off + t + 256, bf) + ldin(b, gb_off + t + 256, bf));
}

// ---------------- MFMA GEMM v6 (N=512 GEMMs: WO K=512, W2 K=2048) ----------------
// Free-run (round-6 verified sync) + compile-time K (full unroll, static LDS addrs) +
// single-shot f32 epilogue (1 lgkm wait instead of 8). Block 256 = 4 waves 2m x 2n;
// tile 128x64; BK=64; always bias + residual + f32 out (the only users).
template <int TK>
__global__ __launch_bounds__(256) void k_gemm3(const u16* __restrict__ A, const u16* __restrict__ BR,
                                               const void* bias, long bias_off,
                                               const float* __restrict__ res, float* __restrict__ outp,
                                               const int* __restrict__ dtflag) {
  constexpr int NKT = TK >> 6;
  int lane = threadIdx.x & 63;
  int wid = threadIdx.x >> 6;
  int wm = wid & 1, wn = wid >> 1;
  int m0 = blockIdx.x * 128;
  int n0 = blockIdx.y * 64;
  int n016 = blockIdx.y * 4;
  constexpr int N16 = 32;  // 512 >> 4

  constexpr int BUFB = 24 * 1024;  // A 16KB + B 8KB per buffer
  __shared__ alignas(16) char smem[2 * BUFB];

  floatx4 acc[4][2];
#pragma unroll
  for (int mi = 0; mi < 4; ++mi)
#pragma unroll
    for (int j = 0; j < 2; ++j)
#pragma unroll
      for (int r = 0; r < 4; ++r) acc[mi][j][r] = 0.0f;

  // A staging: coalesced 8-row x 128B insts, pre-swizzled source
  int arow = lane >> 3;
  int acu = ((lane & 7) ^ arow) * 8;
  const u16* AgS = A + (size_t)(m0 + wid * 32 + arow) * TK + acu;

  auto stage = [&](int kb, int b) {
    u16* aL = (u16*)(smem + b * BUFB);
    u16* bL = aL + 8192;
#pragma unroll
    for (int j = 0; j < 4; ++j)
      ld16(AgS + (size_t)(j * 8) * TK + (size_t)kb * 64, aL + (wid * 4 + j) * 512);
    ld16(BR + (((size_t)(kb * 2) * N16 + n016 + wid) * 64 + lane) * 8, bL + wid * 512);
    ld16(BR + (((size_t)(kb * 2 + 1) * N16 + n016 + wid) * 64 + lane) * 8, bL + 2048 + wid * 512);
  };

  // swizzled A-read offsets (u16)
  int aoff = (lane & 15) * 64;
  int axor = (lane & 7) << 3;
  int ak0 = ((lane >> 4) * 8) ^ axor;
  int ak1 = (32 + (lane >> 4) * 8) ^ axor;

  stage(0, 0);
  stage(1, 1);
  ASM_VMCNT(6);
  __builtin_amdgcn_s_barrier();
  SBAR0();

#pragma unroll
  for (int kb = 0; kb < NKT; ++kb) {
    const u16* aL = (const u16*)(smem + (kb & 1) * BUFB);
    const u16* bL = aL + 8192;
#pragma unroll
    for (int h = 0; h < 2; ++h) {
      int akh = h ? ak1 : ak0;
      bf16x8 afr[4], bfr[2];
#pragma unroll
      for (int mi = 0; mi < 4; ++mi)
        afr[mi] = *(const bf16x8*)(aL + (wm * 4 + mi) * 1024 + aoff + akh);
#pragma unroll
      for (int j = 0; j < 2; ++j)
        bfr[j] = *(const bf16x8*)(bL + h * 2048 + ((wn * 2 + j) * 64 + lane) * 8);
      __builtin_amdgcn_s_setprio(1);
#pragma unroll
      for (int mi = 0; mi < 4; ++mi)
#pragma unroll
        for (int j = 0; j < 2; ++j)
          acc[mi][j] = __builtin_amdgcn_mfma_f32_16x16x32_bf16(afr[mi], bfr[j], acc[mi][j], 0, 0, 0);
      __builtin_amdgcn_s_setprio(0);
    }
    SBAR0();
    __builtin_amdgcn_s_barrier();        // A: all waves done reading live buf
    if (kb + 2 < NKT) {
      stage(kb + 2, kb & 1);
      ASM_VMCNT(6);                      // tile kb+1 landed; kb+2 in flight
    } else if (kb + 1 < NKT) {
      ASM_VMCNT(0);
    }
    __builtin_amdgcn_s_barrier();        // B: landing cross-wave
    SBAR0();
  }

  // ---- epilogue v6: single-shot f32 staging, group-XOR swizzled, 1 wait ----
  // per-wave 64 rows x 32 cols f32 = 8KB (x4 waves = 32KB <= 48KB smem).
  // write: col ^= ((row>>2)&3)<<2  (16B groups; <=2-way on write, 0-conflict read)
  float* epf = (float*)smem + wid * 2048;
  int dtv = *dtflag;
  int nW = n0 + wn * 32;
  int mWb = m0 + wm * 64;
  float bv[2];
#pragma unroll
  for (int j = 0; j < 2; ++j)
    bv[j] = ldin(bias, bias_off + nW + j * 16 + (lane & 15), dtv);
#pragma unroll
  for (int mi = 0; mi < 4; ++mi)
#pragma unroll
    for (int j = 0; j < 2; ++j)
#pragma unroll
      for (int r = 0; r < 4; ++r) {
        int row = mi * 16 + (lane >> 4) * 4 + r;
        int s = (row >> 2) & 3;
        int col = (j * 16 + (lane & 15)) ^ (s << 2);
        epf[row * 32 + col] = acc[mi][j][r] + bv[j];
      }
  asm volatile("s_waitcnt lgkmcnt(0)" ::: "memory");
#pragma unroll
  for (int p = 0; p < 8; ++p) {
    int row = p * 8 + (lane >> 3);
    int s = (row >> 2) & 3;
    int g = (lane & 7) ^ s;
    float4 v = *(const float4*)(epf + row * 32 + g * 4);
    size_t gi = (size_t)(mWb + row) * DIM + nW + (lane & 7) * 4;
    float4 rv = *(const float4*)&res[gi];
    v.x += rv.x; v.y += rv.y; v.z += rv.z; v.w += rv.w;
    *(float4*)&outp[gi] = v;
  }
}

// ---------------- MFMA GEMM v6: 256x256 free-run pipeline (QKV, W1), K=512 ----------
// Round-6 verified sync, now with compile-time K/N (full unroll, static addresses)
// and the single-shot bf16 epilogue (ds_write_b16 + group-XOR swizzle + b128 reads,
// ONE lgkm wait instead of 16).
template <bool HAS_BIAS, bool DO_GELU, int NN>
__device__ __forceinline__ void gemm8_body(const u16* __restrict__ A, const u16* __restrict__ BR,
                                           const void* bias, long bias_off,
                                           u16* __restrict__ outp,
                                           const int* __restrict__ dtflag) {
  constexpr int NKT = GK >> 6;   // 8
  constexpr int N16 = NN >> 4;
  int lane = threadIdx.x & 63;
  int w = threadIdx.x >> 6;       // wave 0..7
  int wm = w >> 2, wn = w & 3;    // 2 x 4
  int m0 = blockIdx.x * 256;
  int n0 = blockIdx.y * 256;
  int n016 = blockIdx.y * 16;

  __shared__ alignas(16) u16 smem8[65536];  // 2 bufs x (A 32KB | B 32KB) = 128 KiB

  int arow = lane >> 3;
  int acu = ((lane & 7) ^ arow) * 8;
  const u16* Ag0 = A + (size_t)(m0 + (w * 2 + 0) * 8 + arow) * GK + acu;
  const u16* Ag1 = A + (size_t)(m0 + (w * 2 + 1) * 8 + arow) * GK + acu;
  const u16* Bg = BR + (size_t)n016 * 512 + lane * 8;

  // stage whole K-tile kt into dbuf: A 4 insts + B 4 insts per wave = 8 loads
  auto stage_full = [&](int kt, int dbuf) {
    u16* aD = smem8 + dbuf * 32768;
    u16* bD = aD + 16384;
    size_t go = (size_t)kt * 64;
#pragma unroll
    for (int half = 0; half < 2; ++half) {
      ld16(Ag0 + (size_t)half * 128 * GK + go, aD + half * 8192 + (w * 2 + 0) * 512);
      ld16(Ag1 + (size_t)half * 128 * GK + go, aD + half * 8192 + (w * 2 + 1) * 512);
    }
#pragma unroll
    for (int kk = 0; kk < 2; ++kk) {
      const u16* s = Bg + ((size_t)(kt * 2 + kk) * N16) * 512;
      ld16(s + (size_t)w * 512,       bD + kk * 8192 + (0 + w) * 512);
      ld16(s + (size_t)(8 + w) * 512, bD + kk * 8192 + (8 + w) * 512);
    }
  };

  int aoff = (lane & 15) * 64;
  int axor = (lane & 7) << 3;
  int ak0 = ((lane >> 4) * 8) ^ axor;
  int ak1 = (32 + (lane >> 4) * 8) ^ axor;

  floatx4 acc[8][4];
#pragma unroll
  for (int mi = 0; mi < 8; ++mi)
#pragma unroll
    for (int j = 0; j < 4; ++j)
#pragma unroll
      for (int r = 0; r < 4; ++r) acc[mi][j][r] = 0.0f;

  stage_full(0, 0);
  stage_full(1, 1);
  ASM_VMCNT(8);
  __builtin_amdgcn_s_barrier();
  SBAR0();

#pragma unroll
  for (int c = 0; c < NKT; ++c) {
    const u16* aL = smem8 + (c & 1) * 32768;
    const u16* bL = aL + 16384;
#pragma unroll
    for (int kk = 0; kk < 2; ++kk) {
      int akh = kk ? ak1 : ak0;
      bf16x8 bfr[4];
#pragma unroll
      for (int i = 0; i < 4; ++i)
        bfr[i] = *(const bf16x8*)(bL + ((kk * 16 + wn * 4 + i) * 64 + lane) * 8);
#pragma unroll
      for (int mh = 0; mh < 2; ++mh) {
        bf16x8 afr[4];
#pragma unroll
        for (int i = 0; i < 4; ++i)
          afr[i] = *(const bf16x8*)(aL + (wm * 8 + mh * 4 + i) * 1024 + aoff + akh);
        __builtin_amdgcn_s_setprio(1);
#pragma unroll
        for (int mi = 0; mi < 4; ++mi)
#pragma unroll
          for (int j = 0; j < 4; ++j)
            acc[mh * 4 + mi][j] =
                __builtin_amdgcn_mfma_f32_16x16x32_bf16(afr[mi], bfr[j], acc[mh * 4 + mi][j], 0, 0, 0);
        __builtin_amdgcn_s_setprio(0);
      }
    }
    SBAR0();
    __builtin_amdgcn_s_barrier();        // A: all waves done reading live buf
    if (c + 2 < NKT) {
      stage_full(c + 2, c & 1);
      ASM_VMCNT(8);                      // tile c+1 landed; c+2 stays in flight
    } else if (c + 1 < NKT) {
      ASM_VMCNT(0);
    }
    __builtin_amdgcn_s_barrier();        // B: landing cross-wave
    SBAR0();
  }

  ASM_VMCNT(0);
  __builtin_amdgcn_s_barrier();

  // ---- epilogue v6: single-shot bf16 staging (per-wave 128x64 = 16KB, 8x = 128KB) ----
  // write bf16 via ds_write_b16 at [row][col ^ (((row>>2)&3)<<3)] (8-col groups),
  // ONE lgkm wait, then 16 passes of conflict-free ds_read_b128 + dwordx4 store.
  u16* epw = smem8 + w * 8192;
  int dtv = HAS_BIAS ? *dtflag : 0;
  int nW = n0 + wn * 64;
  int mW = m0 + wm * 128;
  float bv[4];
#pragma unroll
  for (int j = 0; j < 4; ++j)
    bv[j] = HAS_BIAS ? ldin(bias, bias_off + nW + j * 16 + (lane & 15), dtv) : 0.0f;
#pragma unroll
  for (int mf = 0; mf < 8; ++mf)
#pragma unroll
    for (int j = 0; j < 4; ++j)
#pragma unroll
      for (int r = 0; r < 4; ++r) {
        float v = acc[mf][j][r] + bv[j];
        if (DO_GELU) v = fast_gelu(v);
        int row = mf * 16 + (lane >> 4) * 4 + r;
        int s = (row >> 2) & 3;
        int col = (j * 16 + (lane & 15)) ^ (s << 3);
        epw[row * 64 + col] = f2b(v);
      }
  asm volatile("s_waitcnt lgkmcnt(0)" ::: "memory");
#pragma unroll
  for (int p = 0; p < 16; ++p) {
    int row = p * 8 + (lane >> 3);
    int s = (row >> 2) & 3;
    int g = (lane & 7) ^ s;
    uint4 pk = *(const uint4*)(epw + row * 64 + g * 8);
    size_t gi = (size_t)(mW + row) * NN + nW + (lane & 7) * 8;
    *(uint4*)&outp[gi] = pk;
  }
}

// separately-named instantiations (independent codegen, distinct profile rows)
__global__ __launch_bounds__(512, 2) void k_g8a(const u16* __restrict__ A, const u16* __restrict__ BR,
                                                u16* __restrict__ outp, const int* dtflag) {
  gemm8_body<false, false, QKVW>(A, BR, nullptr, 0, outp, dtflag);
}
__global__ __launch_bounds__(512, 2) void k_g8b(const u16* __restrict__ A, const u16* __restrict__ BR,
                                                const void* bias, long bias_off,
                                                u16* __restrict__ outp, const int* dtflag) {
  gemm8_body<true, true, FFDIM>(A, BR, bias, bias_off, outp, dtflag);
}

// ---------------- attention phase A: per-bucket exp(k)^T v and key sums ----------------
__global__ __launch_bounds__(256) void k_attnA(const u16* __restrict__ qkv,
                                               float* __restrict__ Ksum, float* __restrict__ KV) {
  int u = blockIdx.x & 63;
  int bh = blockIdx.x >> 6;
  int head = bh & 7, batch = bh >> 3;
  int t = threadIdx.x;
  int pr = t >> 2, s = t & 3;
  __shared__ float kex[64][68];
  __shared__ float vv[64][68];
  const u16* base = qkv + (size_t)(batch * SEQ + u * 64 + pr) * QKVW + head * DH;
  uint4 kp0 = *(const uint4*)(base + 512 + s * 16);
  uint4 kp1 = *(const uint4*)(base + 512 + s * 16 + 8);
  uint4 vp0 = *(const uint4*)(base + 1024 + s * 16);
  uint4 vp1 = *(const uint4*)(base + 1024 + s * 16 + 8);
  float kf[16], vf[16];
  unpk8(kp0, kf); unpk8(kp1, kf + 8);
  unpk8(vp0, vf); unpk8(vp1, vf + 8);
#pragma unroll
  for (int i = 0; i < 16; ++i) {
    kex[pr][s * 16 + i] = expf(fminf(kf[i], 30.0f));
    vv[pr][s * 16 + i] = vf[i];
  }
  __syncthreads();
  int d = pr;
  float acc[16];
#pragma unroll
  for (int i = 0; i < 16; ++i) acc[i] = 0.0f;
  float ks = 0.0f;
  for (int p = 0; p < 64; ++p) {
    float kp = kex[p][d];
    ks += kp;
#pragma unroll
    for (int i4 = 0; i4 < 4; ++i4) {
      float4 v4 = *(const float4*)&vv[p][s * 16 + i4 * 4];
      acc[i4 * 4 + 0] += kp * v4.x;
      acc[i4 * 4 + 1] += kp * v4.y;
      acc[i4 * 4 + 2] += kp * v4.z;
      acc[i4 * 4 + 3] += kp * v4.w;
    }
  }
  float* kvout = KV + (size_t)blockIdx.x * 4096 + d * 64 + s * 16;
#pragma unroll
  for (int i4 = 0; i4 < 4; ++i4) {
    float4 o; o.x = acc[i4 * 4]; o.y = acc[i4 * 4 + 1]; o.z = acc[i4 * 4 + 2]; o.w = acc[i4 * 4 + 3];
    *(float4*)(kvout + i4 * 4) = o;
  }
  if (s == 0) Ksum[(size_t)blockIdx.x * 64 + d] = ks;
}

// ---------------- attention phase B: exclusive prefix over buckets ----------------
__global__ __launch_bounds__(64) void k_scan2(float* __restrict__ Ksum, float* __restrict__ KV) {
  int bh = blockIdx.x >> 6;
  int d = blockIdx.x & 63;
  int e = threadIdx.x;
  float* p0 = KV + (size_t)bh * 64 * 4096 + d * 64 + e;
  float v[64];
#pragma unroll
  for (int u = 0; u < 64; ++u) v[u] = p0[(size_t)u * 4096];
  float run = 0.0f;
#pragma unroll
  for (int u = 0; u < 64; ++u) { float c = v[u]; v[u] = run; run += c; }
#pragma unroll
  for (int u = 0; u < 64; ++u) p0[(size_t)u * 4096] = v[u];
  if (d == 0) {
    float* kp = Ksum + (size_t)bh * 4096 + e;
    float sv[64];
#pragma unroll
    for (int u = 0; u < 64; ++u) sv[u] = kp[u * 64];
    float r = 0.0f;
#pragma unroll
    for (int u = 0; u < 64; ++u) { float c = sv[u]; sv[u] = r; r += c; }
#pragma unroll
    for (int u = 0; u < 64; ++u) kp[u * 64] = sv[u];
  }
}

// ---------------- attention phase C: softmax(q), D, output ----------------
__global__ __launch_bounds__(256) void k_attnC(const u16* __restrict__ qkv, const float* __restrict__ Ksum,
                                               const float* __restrict__ KV, u16* __restrict__ att) {
  int u = blockIdx.x & 63;
  int bh = blockIdx.x >> 6;
  int head = bh & 7, batch = bh >> 3;
  int t = threadIdx.x;
  int pos = t >> 2, s = t & 3;
  __shared__ float Cm[64][68];
  __shared__ float qs[64][68];
  __shared__ float S[64];
  const float* kvb = KV + (size_t)blockIdx.x * 4096 + pos * 64 + s * 16;
#pragma unroll
  for (int i4 = 0; i4 < 4; ++i4)
    *(float4*)&Cm[pos][s * 16 + i4 * 4] = *(const float4*)(kvb + i4 * 4);
  if (t < 64) S[t] = Ksum[(size_t)blockIdx.x * 64 + t];
  size_t grow = (size_t)(batch * SEQ + u * 64 + pos) * QKVW + head * DH;
  uint4 q0 = *(const uint4*)(qkv + grow + s * 16);
  uint4 q1 = *(const uint4*)(qkv + grow + s * 16 + 8);
  float q[16];
  unpk8(q0, q); unpk8(q1, q + 8);
  float mx = q[0];
#pragma unroll
  for (int i = 1; i < 16; ++i) mx = fmaxf(mx, q[i]);
  mx = fmaxf(mx, __shfl_xor(mx, 1));
  mx = fmaxf(mx, __shfl_xor(mx, 2));
  float sum = 0.0f;
#pragma unroll
  for (int i = 0; i < 16; ++i) { q[i] = expf(q[i] - mx); sum += q[i]; }
  sum += __shfl_xor(sum, 1);
  sum += __shfl_xor(sum, 2);
  float scale = 0.125f / sum;  // * e^-0.5 with e=64
  __syncthreads();  // S ready
  float Dp = 0.0f;
#pragma unroll
  for (int i = 0; i < 16; ++i) { q[i] *= scale; Dp += q[i] * S[s * 16 + i]; }
  Dp += __shfl_xor(Dp, 1);
  Dp += __shfl_xor(Dp, 2);
  float Dinv = 1.0f / fmaxf(Dp, 1e-3f);
#pragma unroll
  for (int i = 0; i < 16; ++i) qs[pos][s * 16 + i] = q[i];
  __syncthreads();  // Cm + qs ready
  float o[16];
#pragma unroll
  for (int i = 0; i < 16; ++i) o[i] = 0.0f;
  for (int d = 0; d < 64; ++d) {
    float qd = qs[pos][d];
#pragma unroll
    for (int i4 = 0; i4 < 4; ++i4) {
      float4 c4 = *(const float4*)&Cm[d][s * 16 + i4 * 4];
      o[i4 * 4 + 0] += qd * c4.x;
      o[i4 * 4 + 1] += qd * c4.y;
      o[i4 * 4 + 2] += qd * c4.z;
      o[i4 * 4 + 3] += qd * c4.w;
    }
  }
  u16* orow = att + (size_t)(batch * SEQ + u * 64 + pos) * DIM + head * DH + s * 16;
  uint4 pk0, pk1;
  pk0.x = (unsigned)f2b(o[0] * Dinv) | ((unsigned)f2b(o[1] * Dinv) << 16);
  pk0.y = (unsigned)f2b(o[2] * Dinv) | ((unsigned)f2b(o[3] * Dinv) << 16);
  pk0.z = (unsigned)f2b(o[4] * Dinv) | ((unsigned)f2b(o[5] * Dinv) << 16);
  pk0.w = (unsigned)f2b(o[6] * Dinv) | ((unsigned)f2b(o[7] * Dinv) << 16);
  pk1.x = (unsigned)f2b(o[8] * Dinv) | ((unsigned)f2b(o[9] * Dinv) << 16);
  pk1.y = (unsigned)f2b(o[10] * Dinv) | ((unsigned)f2b(o[11] * Dinv) << 16);
  pk1.z = (unsigned)f2b(o[12] * Dinv) | ((unsigned)f2b(o[13] * Dinv) << 16);
  pk1.w = (unsigned)f2b(o[14] * Dinv) | ((unsigned)f2b(o[15] * Dinv) << 16);
  *(uint4*)orow = pk0;
  *(uint4*)(orow + 8) = pk1;
}

// ---------------- host orchestration ----------------
extern "C" void kernel_launch(void* const* d_in, const int* in_sizes, int n_in,
                              void* d_out, int out_size, void* d_ws, size_t ws_size,
                              hipStream_t stream) {
  (void)in_sizes; (void)n_in; (void)out_size; (void)ws_size;
  const void* x_in = d_in[0];
  const void* ln1_g = d_in[1];
  const void* ln1_b = d_in[2];
  const void* wq = d_in[3];
  const void* wk = d_in[4];
  const void* wv = d_in[5];
  const void* wo = d_in[6];
  const void* bo = d_in[7];
  const void* ln2_g = d_in[8];
  const void* ln2_b = d_in[9];
  const void* w1 = d_in[10];
  const void* b1 = d_in[11];
  const void* w2 = d_in[12];
  const void* b2 = d_in[13];

  char* ws = (char*)d_ws;
  float* xf = (float*)(ws);              // 16 MiB f32 residual
  u16* h = (u16*)(ws + 16777216);        // 8 MiB bf16
  u16* region = (u16*)(ws + 25165824);   // 32 MiB: qkv (24 MiB) / gb (32 MiB)
  float* Ksum = (float*)(ws + 58720256); // 256 KiB
  float* KV = (float*)(ws + 58982400);   // 16 MiB
  u16* WR = (u16*)(ws + 75759616);       // 24 MiB repacked weights
  int* dt = (int*)(ws + 100925440);      // dtype flag
  u16* qkv = region;
  u16* gb = region;

  auto WqkvR = [&](int i) { return WR + (size_t)i * LSTRIDE + 0; };
  auto WoR   = [&](int i) { return WR + (size_t)i * LSTRIDE + 786432; };
  auto W1R   = [&](int i) { return WR + (size_t)i * LSTRIDE + 1048576; };
  auto W2R   = [&](int i) { return WR + (size_t)i * LSTRIDE + 2097152; };

  k_detect<<<dim3(1), dim3(1), 0, stream>>>(ln1_g, dt);

  const int nx = ROWS * DIM;
  k_x2f<<<dim3((nx + 255) / 256), dim3(256), 0, stream>>>(x_in, xf, nx, dt);

  k_repackQ<<<dim3(16, 8, 16), dim3(256), 0, stream>>>(wq, wk, wv, wo, WR, dt);
  k_repackF1<<<dim3(16, 32, 4), dim3(256), 0, stream>>>(w1, WR, dt);
  k_repackF2<<<dim3(64, 8, 4), dim3(256), 0, stream>>>(w2, WR, dt);

  for (int i = 0; i < 4; ++i) {
    // PreNorm(attn)
    k_ln<<<dim3(ROWS), dim3(256), 0, stream>>>(xf, ln1_g, ln1_b, (long)i * DIM, h, dt);
    // fused QKV gemm: [8192,512] @ [512,1536]
    k_g8a<<<dim3(32, 6), dim3(512), 0, stream>>>(h, WqkvR(i), qkv, dt);
    k_attnA<<<dim3(1024), dim3(256), 0, stream>>>(qkv, Ksum, KV);
    k_scan2<<<dim3(1024), dim3(64), 0, stream>>>(Ksum, KV);
    k_attnC<<<dim3(1024), dim3(256), 0, stream>>>(qkv, Ksum, KV, h);  // att -> h
    // x += att @ wo + bo  (N=512, K=512)
    k_gemm3<512><<<dim3(64, 8), dim3(256), 0, stream>>>(h, WoR(i), bo, (long)i * DIM, xf, xf, dt);
    // PreNorm(FF)
    k_ln<<<dim3(ROWS), dim3(256), 0, stream>>>(xf, ln2_g, ln2_b, (long)i * DIM, h, dt);
    // FF up: [8192,512] @ [512,2048] + bias + gelu
    k_g8b<<<dim3(32, 8), dim3(512), 0, stream>>>(h, W1R(i), b1, (long)i * FFDIM, gb, dt);
    // FF down: [8192,2048] @ [2048,512] + bias + residual (N=512, K=2048)
    k_gemm3<2048><<<dim3(64, 8), dim3(256), 0, stream>>>(gb, W2R(i), b2, (long)i * DIM, xf, xf, dt);
  }

  k_store<<<dim3((nx + 255) / 256), dim3(256), 0, stream>>>(xf, d_out, nx, dt);
}

// Round 8
// 664.970 us; speedup vs baseline: 1.2859x; 1.1453x over previous
//
#include <hip/hip_runtime.h>

// ---------------- types / helpers ----------------
typedef unsigned short u16;
typedef __bf16 bf16x8 __attribute__((ext_vector_type(8)));
typedef float floatx4 __attribute__((ext_vector_type(4)));

#define DIM 512
#define HEADS 8
#define DH 64
#define SEQ 4096
#define BATCH 2
#define ROWS (BATCH * SEQ) /* 8192 */
#define FFDIM 2048
#define QKVW 1536 /* fused qkv row width */
#define LSTRIDE 3145728L /* repacked weight elems per layer */
#define GK 512   /* K of all gemm8 GEMMs (QKV, W1) */

#define SBAR0() __builtin_amdgcn_sched_barrier(0)
#define ASM_VMCNT(n) asm volatile("s_waitcnt vmcnt(" #n ")" ::: "memory")

__device__ __forceinline__ float b2f(u16 u) {
  union { float f; unsigned int i; } c; c.i = ((unsigned int)u) << 16; return c.f;
}
__device__ __forceinline__ u16 f2b(float f) {
  union { float f; unsigned int i; } c; c.f = f;
  unsigned int r = c.i + 0x7FFFu + ((c.i >> 16) & 1u);
  return (u16)(r >> 16);
}
__device__ __forceinline__ float ldin(const void* p, long i, int bf) {
  return bf ? b2f(((const u16*)p)[i]) : ((const float*)p)[i];
}
// async global->LDS, 16 bytes/lane. LDS dest = base + lane*16 (HW); global addr per-lane.
__device__ __forceinline__ void ld16(const u16* g, u16* l) {
  __builtin_amdgcn_global_load_lds((const __attribute__((address_space(1))) void*)g,
                                   (__attribute__((address_space(3))) void*)l, 16, 0, 0);
}
// unpack 8 u16 (as uint4) -> 8 floats
__device__ __forceinline__ void unpk8(uint4 p, float* o) {
  o[0] = b2f((u16)(p.x & 0xFFFF)); o[1] = b2f((u16)(p.x >> 16));
  o[2] = b2f((u16)(p.y & 0xFFFF)); o[3] = b2f((u16)(p.y >> 16));
  o[4] = b2f((u16)(p.z & 0xFFFF)); o[5] = b2f((u16)(p.z >> 16));
  o[6] = b2f((u16)(p.w & 0xFFFF)); o[7] = b2f((u16)(p.w >> 16));
}
// exact-enough GELU: erf via Abramowitz-Stegun 7.1.26 (|err| <= 1.5e-7) + fast exp.
__device__ __forceinline__ float fast_gelu(float v) {
  float z = fabsf(v) * 0.70710678118654752f;
  float t = 1.0f / (1.0f + 0.3275911f * z);
  float p = t * (0.254829592f +
           t * (-0.284496736f +
           t * (1.421413741f +
           t * (-1.453152027f +
           t * 1.061405429f))));
  float e = __expf(-z * z);
  float er = 1.0f - p * e;             // erf(|z|)
  float s = copysignf(er, v);          // erf(z)
  return 0.5f * v * (1.0f + s);
}

// ---------------- dtype detection ----------------
__global__ void k_detect(const void* __restrict__ g, int* __restrict__ flag) {
  *flag = (((const u16*)g)[0] == 0x3F80u) ? 1 : 0;
}

// ---------------- input x -> f32 / f32 -> out ----------------
__global__ __launch_bounds__(256) void k_x2f(const void* __restrict__ in, float* __restrict__ out,
                                             int n, const int* __restrict__ dt) {
  int bf = *dt;
  int i = blockIdx.x * 256 + threadIdx.x;
  if (i < n) out[i] = ldin(in, i, bf);
}
__global__ __launch_bounds__(256) void k_store(const float* __restrict__ in, void* __restrict__ out,
                                               int n, const int* __restrict__ dt) {
  int bf = *dt;
  int i = blockIdx.x * 256 + threadIdx.x;
  if (i < n) {
    if (bf) ((u16*)out)[i] = f2b(in[i]);
    else ((float*)out)[i] = in[i];
  }
}

// ---------------- weight repack (LDS-tiled, coalesced, batched) ----------------
__device__ __forceinline__ void repack_tile(const void* W, long w_off, u16* R, int N,
                                            int n16tot, int j_off, int kb, int jb, int bf) {
  int t = threadIdx.x;
  __shared__ float tile[32][65];
  int r0 = t >> 6;
  int c = t & 63;
#pragma unroll
  for (int i = 0; i < 8; ++i) {
    int rr = i * 4 + r0;
    tile[rr][c] = ldin(W, w_off + (long)(kb * 32 + rr) * N + jb * 64 + c, bf);
  }
  __syncthreads();
  int lane = t & 63, w = t >> 6;
  alignas(16) u16 tmp[8];
#pragma unroll
  for (int r = 0; r < 8; ++r) tmp[r] = f2b(tile[(lane >> 4) * 8 + r][w * 16 + (lane & 15)]);
  long oidx = (((long)kb * n16tot + j_off + jb * 4 + w) * 64 + lane) * 8;
  *(uint4*)(R + oidx) = *(const uint4*)tmp;
}
// all 512x512 weights: grid (16,8,16); z = layer*4 + type(0=q,1=k,2=v,3=o)
__global__ __launch_bounds__(256) void k_repackQ(const void* wq, const void* wk,
                                                 const void* wv, const void* wo,
                                                 u16* WR, const int* __restrict__ dt) {
  int bf = *dt;
  int z = blockIdx.z, layer = z >> 2, type = z & 3;
  const void* W = (type == 0) ? wq : (type == 1) ? wk : (type == 2) ? wv : wo;
  u16* R = WR + (long)layer * LSTRIDE + (type < 3 ? 0 : 786432);
  int n16tot = (type < 3) ? 96 : 32;
  int j_off = (type < 3) ? type * 32 : 0;
  repack_tile(W, (long)layer * 262144, R, 512, n16tot, j_off, blockIdx.x, blockIdx.y, bf);
}
// w1: grid (16,32,4)
__global__ __launch_bounds__(256) void k_repackF1(const void* w1, u16* WR, const int* __restrict__ dt) {
  int bf = *dt;
  repack_tile(w1, (long)blockIdx.z * 1048576, WR + (long)blockIdx.z * LSTRIDE + 1048576,
              2048, 128, 0, blockIdx.x, blockIdx.y, bf);
}
// w2: grid (64,8,4)
__global__ __launch_bounds__(256) void k_repackF2(const void* w2, u16* WR, const int* __restrict__ dt) {
  int bf = *dt;
  repack_tile(w2, (long)blockIdx.z * 1048576, WR + (long)blockIdx.z * LSTRIDE + 2097152,
              512, 32, 0, blockIdx.x, blockIdx.y, bf);
}

// ---------------- layernorm (f32 in, bf16 out) ----------------
__global__ __launch_bounds__(256) void k_ln(const float* __restrict__ x,
                                            const void* __restrict__ g, const void* __restrict__ b,
                                            long gb_off, u16* __restrict__ out,
                                            const int* __restrict__ dt) {
  int bf = *dt;
  int row = blockIdx.x;
  int t = threadIdx.x;
  const float* xr = x + (size_t)row * DIM;
  float v0 = xr[t], v1 = xr[t + 256];
  float s = v0 + v1;
  float s2 = v0 * v0 + v1 * v1;
#pragma unroll
  for (int off = 32; off > 0; off >>= 1) {
    s += __shfl_down(s, off);
    s2 += __shfl_down(s2, off);
  }
  __shared__ float red[8];
  int lane = t & 63, w = t >> 6;
  if (lane == 0) { red[w] = s; red[4 + w] = s2; }
  __syncthreads();
  float ts = red[0] + red[1] + red[2] + red[3];
  float ts2 = red[4] + red[5] + red[6] + red[7];
  float mean = ts * (1.0f / DIM);
  float var = ts2 * (1.0f / DIM) - mean * mean;
  float rstd = rsqrtf(var + 1e-5f);
  u16* orow = out + (size_t)row * DIM;
  orow[t] = f2b((v0 - mean) * rstd * ldin(g, gb_off + t, bf) + ldin(b, gb_off + t, bf));
  orow[t + 256] = f2b((v1 - mean) * rstd * ldin(g, gb_off + t + 256, bf) + ldin(b, gb_off + t + 256, bf));
}

// ---------------- MFMA GEMM v6 (N=512 GEMMs: WO K=512, W2 K=2048) ----------------
template <int TK>
__global__ __launch_bounds__(256) void k_gemm3(const u16* __restrict__ A, const u16* __restrict__ BR,
                                               const void* bias, long bias_off,
                                               const float* __restrict__ res, float* __restrict__ outp,
                                               const int* __restrict__ dtflag) {
  constexpr int NKT = TK >> 6;
  int lane = threadIdx.x & 63;
  int wid = threadIdx.x >> 6;
  int wm = wid & 1, wn = wid >> 1;
  int m0 = blockIdx.x * 128;
  int n0 = blockIdx.y * 64;
  int n016 = blockIdx.y * 4;
  constexpr int N16 = 32;  // 512 >> 4

  constexpr int BUFB = 24 * 1024;  // A 16KB + B 8KB per buffer
  __shared__ alignas(16) char smem[2 * BUFB];

  floatx4 acc[4][2];
#pragma unroll
  for (int mi = 0; mi < 4; ++mi)
#pragma unroll
    for (int j = 0; j < 2; ++j)
#pragma unroll
      for (int r = 0; r < 4; ++r) acc[mi][j][r] = 0.0f;

  // A staging: coalesced 8-row x 128B insts, pre-swizzled source
  int arow = lane >> 3;
  int acu = ((lane & 7) ^ arow) * 8;
  const u16* AgS = A + (size_t)(m0 + wid * 32 + arow) * TK + acu;

  auto stage = [&](int kb, int b) {
    u16* aL = (u16*)(smem + b * BUFB);
    u16* bL = aL + 8192;
#pragma unroll
    for (int j = 0; j < 4; ++j)
      ld16(AgS + (size_t)(j * 8) * TK + (size_t)kb * 64, aL + (wid * 4 + j) * 512);
    ld16(BR + (((size_t)(kb * 2) * N16 + n016 + wid) * 64 + lane) * 8, bL + wid * 512);
    ld16(BR + (((size_t)(kb * 2 + 1) * N16 + n016 + wid) * 64 + lane) * 8, bL + 2048 + wid * 512);
  };

  // swizzled A-read offsets (u16)
  int aoff = (lane & 15) * 64;
  int axor = (lane & 7) << 3;
  int ak0 = ((lane >> 4) * 8) ^ axor;
  int ak1 = (32 + (lane >> 4) * 8) ^ axor;

  stage(0, 0);
  stage(1, 1);
  ASM_VMCNT(6);
  __builtin_amdgcn_s_barrier();
  SBAR0();

#pragma unroll
  for (int kb = 0; kb < NKT; ++kb) {
    const u16* aL = (const u16*)(smem + (kb & 1) * BUFB);
    const u16* bL = aL + 8192;
#pragma unroll
    for (int h = 0; h < 2; ++h) {
      int akh = h ? ak1 : ak0;
      bf16x8 afr[4], bfr[2];
#pragma unroll
      for (int mi = 0; mi < 4; ++mi)
        afr[mi] = *(const bf16x8*)(aL + (wm * 4 + mi) * 1024 + aoff + akh);
#pragma unroll
      for (int j = 0; j < 2; ++j)
        bfr[j] = *(const bf16x8*)(bL + h * 2048 + ((wn * 2 + j) * 64 + lane) * 8);
      __builtin_amdgcn_s_setprio(1);
#pragma unroll
      for (int mi = 0; mi < 4; ++mi)
#pragma unroll
        for (int j = 0; j < 2; ++j)
          acc[mi][j] = __builtin_amdgcn_mfma_f32_16x16x32_bf16(afr[mi], bfr[j], acc[mi][j], 0, 0, 0);
      __builtin_amdgcn_s_setprio(0);
    }
    SBAR0();
    __builtin_amdgcn_s_barrier();        // A: all waves done reading live buf
    if (kb + 2 < NKT) {
      stage(kb + 2, kb & 1);
      ASM_VMCNT(6);                      // tile kb+1 landed; kb+2 in flight
    } else if (kb + 1 < NKT) {
      ASM_VMCNT(0);
    }
    __builtin_amdgcn_s_barrier();        // B: landing cross-wave
    SBAR0();
  }

  // ---- epilogue v6: single-shot f32 staging, group-XOR swizzled, 1 wait ----
  float* epf = (float*)smem + wid * 2048;
  int dtv = *dtflag;
  int nW = n0 + wn * 32;
  int mWb = m0 + wm * 64;
  float bv[2];
#pragma unroll
  for (int j = 0; j < 2; ++j)
    bv[j] = ldin(bias, bias_off + nW + j * 16 + (lane & 15), dtv);
#pragma unroll
  for (int mi = 0; mi < 4; ++mi)
#pragma unroll
    for (int j = 0; j < 2; ++j)
#pragma unroll
      for (int r = 0; r < 4; ++r) {
        int row = mi * 16 + (lane >> 4) * 4 + r;
        int s = (row >> 2) & 3;
        int col = (j * 16 + (lane & 15)) ^ (s << 2);
        epf[row * 32 + col] = acc[mi][j][r] + bv[j];
      }
  asm volatile("s_waitcnt lgkmcnt(0)" ::: "memory");
#pragma unroll
  for (int p = 0; p < 8; ++p) {
    int row = p * 8 + (lane >> 3);
    int s = (row >> 2) & 3;
    int g = (lane & 7) ^ s;
    float4 v = *(const float4*)(epf + row * 32 + g * 4);
    size_t gi = (size_t)(mWb + row) * DIM + nW + (lane & 7) * 4;
    float4 rv = *(const float4*)&res[gi];
    v.x += rv.x; v.y += rv.y; v.z += rv.z; v.w += rv.w;
    *(float4*)&outp[gi] = v;
  }
}

// ---------------- MFMA GEMM v6: 256x256 free-run pipeline (QKV, W1), K=512 ----------
template <bool HAS_BIAS, bool DO_GELU, int NN>
__device__ __forceinline__ void gemm8_body(const u16* __restrict__ A, const u16* __restrict__ BR,
                                           const void* bias, long bias_off,
                                           u16* __restrict__ outp,
                                           const int* __restrict__ dtflag) {
  constexpr int NKT = GK >> 6;   // 8
  constexpr int N16 = NN >> 4;
  int lane = threadIdx.x & 63;
  int w = threadIdx.x >> 6;       // wave 0..7
  int wm = w >> 2, wn = w & 3;    // 2 x 4
  int m0 = blockIdx.x * 256;
  int n0 = blockIdx.y * 256;
  int n016 = blockIdx.y * 16;

  __shared__ alignas(16) u16 smem8[65536];  // 2 bufs x (A 32KB | B 32KB) = 128 KiB

  int arow = lane >> 3;
  int acu = ((lane & 7) ^ arow) * 8;
  const u16* Ag0 = A + (size_t)(m0 + (w * 2 + 0) * 8 + arow) * GK + acu;
  const u16* Ag1 = A + (size_t)(m0 + (w * 2 + 1) * 8 + arow) * GK + acu;
  const u16* Bg = BR + (size_t)n016 * 512 + lane * 8;

  auto stage_full = [&](int kt, int dbuf) {
    u16* aD = smem8 + dbuf * 32768;
    u16* bD = aD + 16384;
    size_t go = (size_t)kt * 64;
#pragma unroll
    for (int half = 0; half < 2; ++half) {
      ld16(Ag0 + (size_t)half * 128 * GK + go, aD + half * 8192 + (w * 2 + 0) * 512);
      ld16(Ag1 + (size_t)half * 128 * GK + go, aD + half * 8192 + (w * 2 + 1) * 512);
    }
#pragma unroll
    for (int kk = 0; kk < 2; ++kk) {
      const u16* s = Bg + ((size_t)(kt * 2 + kk) * N16) * 512;
      ld16(s + (size_t)w * 512,       bD + kk * 8192 + (0 + w) * 512);
      ld16(s + (size_t)(8 + w) * 512, bD + kk * 8192 + (8 + w) * 512);
    }
  };

  int aoff = (lane & 15) * 64;
  int axor = (lane & 7) << 3;
  int ak0 = ((lane >> 4) * 8) ^ axor;
  int ak1 = (32 + (lane >> 4) * 8) ^ axor;

  floatx4 acc[8][4];
#pragma unroll
  for (int mi = 0; mi < 8; ++mi)
#pragma unroll
    for (int j = 0; j < 4; ++j)
#pragma unroll
      for (int r = 0; r < 4; ++r) acc[mi][j][r] = 0.0f;

  stage_full(0, 0);
  stage_full(1, 1);
  ASM_VMCNT(8);
  __builtin_amdgcn_s_barrier();
  SBAR0();

#pragma unroll
  for (int c = 0; c < NKT; ++c) {
    const u16* aL = smem8 + (c & 1) * 32768;
    const u16* bL = aL + 16384;
#pragma unroll
    for (int kk = 0; kk < 2; ++kk) {
      int akh = kk ? ak1 : ak0;
      bf16x8 bfr[4];
#pragma unroll
      for (int i = 0; i < 4; ++i)
        bfr[i] = *(const bf16x8*)(bL + ((kk * 16 + wn * 4 + i) * 64 + lane) * 8);
#pragma unroll
      for (int mh = 0; mh < 2; ++mh) {
        bf16x8 afr[4];
#pragma unroll
        for (int i = 0; i < 4; ++i)
          afr[i] = *(const bf16x8*)(aL + (wm * 8 + mh * 4 + i) * 1024 + aoff + akh);
        __builtin_amdgcn_s_setprio(1);
#pragma unroll
        for (int mi = 0; mi < 4; ++mi)
#pragma unroll
          for (int j = 0; j < 4; ++j)
            acc[mh * 4 + mi][j] =
                __builtin_amdgcn_mfma_f32_16x16x32_bf16(afr[mi], bfr[j], acc[mh * 4 + mi][j], 0, 0, 0);
        __builtin_amdgcn_s_setprio(0);
      }
    }
    SBAR0();
    __builtin_amdgcn_s_barrier();        // A: all waves done reading live buf
    if (c + 2 < NKT) {
      stage_full(c + 2, c & 1);
      ASM_VMCNT(8);                      // tile c+1 landed; c+2 stays in flight
    } else if (c + 1 < NKT) {
      ASM_VMCNT(0);
    }
    __builtin_amdgcn_s_barrier();        // B: landing cross-wave
    SBAR0();
  }

  ASM_VMCNT(0);
  __builtin_amdgcn_s_barrier();

  // ---- epilogue v6: single-shot bf16 staging ----
  u16* epw = smem8 + w * 8192;
  int dtv = HAS_BIAS ? *dtflag : 0;
  int nW = n0 + wn * 64;
  int mW = m0 + wm * 128;
  float bv[4];
#pragma unroll
  for (int j = 0; j < 4; ++j)
    bv[j] = HAS_BIAS ? ldin(bias, bias_off + nW + j * 16 + (lane & 15), dtv) : 0.0f;
#pragma unroll
  for (int mf = 0; mf < 8; ++mf)
#pragma unroll
    for (int j = 0; j < 4; ++j)
#pragma unroll
      for (int r = 0; r < 4; ++r) {
        float v = acc[mf][j][r] + bv[j];
        if (DO_GELU) v = fast_gelu(v);
        int row = mf * 16 + (lane >> 4) * 4 + r;
        int s = (row >> 2) & 3;
        int col = (j * 16 + (lane & 15)) ^ (s << 3);
        epw[row * 64 + col] = f2b(v);
      }
  asm volatile("s_waitcnt lgkmcnt(0)" ::: "memory");
#pragma unroll
  for (int p = 0; p < 16; ++p) {
    int row = p * 8 + (lane >> 3);
    int s = (row >> 2) & 3;
    int g = (lane & 7) ^ s;
    uint4 pk = *(const uint4*)(epw + row * 64 + g * 8);
    size_t gi = (size_t)(mW + row) * NN + nW + (lane & 7) * 8;
    *(uint4*)&outp[gi] = pk;
  }
}

// separately-named instantiations (independent codegen, distinct profile rows)
__global__ __launch_bounds__(512, 2) void k_g8a(const u16* __restrict__ A, const u16* __restrict__ BR,
                                                u16* __restrict__ outp, const int* dtflag) {
  gemm8_body<false, false, QKVW>(A, BR, nullptr, 0, outp, dtflag);
}
__global__ __launch_bounds__(512, 2) void k_g8b(const u16* __restrict__ A, const u16* __restrict__ BR,
                                                const void* bias, long bias_off,
                                                u16* __restrict__ outp, const int* dtflag) {
  gemm8_body<true, true, FFDIM>(A, BR, bias, bias_off, outp, dtflag);
}

// ---------------- attention phase A v2: MFMA exp(K)^T @ V ----------------
// grid 1024 = bh*64+u ; block 256 = 4 waves. LDS: expk/v transposed bf16, XOR-swizzled
// (col ^= (row&7)<<3; 8-granule contiguity preserved -> b128 frag reads at the even-
// distribution floor). Wave w computes KV rows d in [w*16, w*16+16): 2 kc x 4 nf MFMAs.
// Ksum recomputed from the SAME bf16 expk (numerator/denominator consistent).
__global__ __launch_bounds__(256) void k_attnA(const u16* __restrict__ qkv,
                                               float* __restrict__ Ksum, float* __restrict__ KV) {
  int u = blockIdx.x & 63;
  int bh = blockIdx.x >> 6;
  int head = bh & 7, batch = bh >> 3;
  int t = threadIdx.x;
  __shared__ u16 ekt[4096];   // ekt[d][p^swz] = bf16(exp(k[p][d]))
  __shared__ u16 vt[4096];    // vt[e][p^swz]  = v[p][e]
  __shared__ float ks4[4][64];
  {
    int pr = t >> 2, s = t & 3;
    const u16* base = qkv + (size_t)(batch * SEQ + u * 64 + pr) * QKVW + head * DH;
    uint4 kp0 = *(const uint4*)(base + 512 + s * 16);
    uint4 kp1 = *(const uint4*)(base + 512 + s * 16 + 8);
    uint4 vp0 = *(const uint4*)(base + 1024 + s * 16);
    uint4 vp1 = *(const uint4*)(base + 1024 + s * 16 + 8);
    float kf[16];
    unpk8(kp0, kf); unpk8(kp1, kf + 8);
    u16 vu[16];
    vu[0] = (u16)vp0.x; vu[1] = (u16)(vp0.x >> 16); vu[2] = (u16)vp0.y; vu[3] = (u16)(vp0.y >> 16);
    vu[4] = (u16)vp0.z; vu[5] = (u16)(vp0.z >> 16); vu[6] = (u16)vp0.w; vu[7] = (u16)(vp0.w >> 16);
    vu[8] = (u16)vp1.x; vu[9] = (u16)(vp1.x >> 16); vu[10] = (u16)vp1.y; vu[11] = (u16)(vp1.y >> 16);
    vu[12] = (u16)vp1.z; vu[13] = (u16)(vp1.z >> 16); vu[14] = (u16)vp1.w; vu[15] = (u16)(vp1.w >> 16);
#pragma unroll
    for (int i = 0; i < 16; ++i) {
      int row = s * 16 + i;
      int col = pr ^ ((i & 7) << 3);
      ekt[row * 64 + col] = f2b(expf(fminf(kf[i], 30.0f)));
      vt[row * 64 + col] = vu[i];
    }
  }
  __syncthreads();
  int w = t >> 6, l = t & 63;
  int X = (l & 7) << 3;
  // Ksum partials: wave w sums p-quarter w for d=l
  {
    uint4 e0 = *(const uint4*)(ekt + l * 64 + ((w * 16) ^ X));
    uint4 e1 = *(const uint4*)(ekt + l * 64 + ((w * 16 + 8) ^ X));
    float f0[8], f1[8];
    unpk8(e0, f0); unpk8(e1, f1);
    float ssum = 0.0f;
#pragma unroll
    for (int i = 0; i < 8; ++i) ssum += f0[i] + f1[i];
    ks4[w][l] = ssum;
  }
  // MFMA: KV[d][e] = sum_p expk[p][d] * v[p][e]
  floatx4 acc[4];
#pragma unroll
  for (int nf = 0; nf < 4; ++nf)
#pragma unroll
    for (int r = 0; r < 4; ++r) acc[nf][r] = 0.0f;
  int dl = w * 16 + (l & 15);
#pragma unroll
  for (int kc = 0; kc < 2; ++kc) {
    int poff = kc * 32 + (l >> 4) * 8;
    bf16x8 afr = *(const bf16x8*)(ekt + dl * 64 + (poff ^ X));
#pragma unroll
    for (int nf = 0; nf < 4; ++nf) {
      bf16x8 bfr = *(const bf16x8*)(vt + (nf * 16 + (l & 15)) * 64 + (poff ^ X));
      acc[nf] = __builtin_amdgcn_mfma_f32_16x16x32_bf16(afr, bfr, acc[nf], 0, 0, 0);
    }
  }
  float* kvout = KV + (size_t)blockIdx.x * 4096;
#pragma unroll
  for (int nf = 0; nf < 4; ++nf)
#pragma unroll
    for (int r = 0; r < 4; ++r) {
      int d = w * 16 + (l >> 4) * 4 + r;
      kvout[d * 64 + nf * 16 + (l & 15)] = acc[nf][r];
    }
  __syncthreads();
  if (t < 64) Ksum[(size_t)blockIdx.x * 64 + t] = ks4[0][t] + ks4[1][t] + ks4[2][t] + ks4[3][t];
}

// ---------------- attention phase B: exclusive prefix over buckets ----------------
__global__ __launch_bounds__(64) void k_scan2(float* __restrict__ Ksum, float* __restrict__ KV) {
  int bh = blockIdx.x >> 6;
  int d = blockIdx.x & 63;
  int e = threadIdx.x;
  float* p0 = KV + (size_t)bh * 64 * 4096 + d * 64 + e;
  float v[64];
#pragma unroll
  for (int u = 0; u < 64; ++u) v[u] = p0[(size_t)u * 4096];
  float run = 0.0f;
#pragma unroll
  for (int u = 0; u < 64; ++u) { float c = v[u]; v[u] = run; run += c; }
#pragma unroll
  for (int u = 0; u < 64; ++u) p0[(size_t)u * 4096] = v[u];
  if (d == 0) {
    float* kp = Ksum + (size_t)bh * 4096 + e;
    float sv[64];
#pragma unroll
    for (int u = 0; u < 64; ++u) sv[u] = kp[u * 64];
    float r = 0.0f;
#pragma unroll
    for (int u = 0; u < 64; ++u) { float c = sv[u]; sv[u] = r; r += c; }
#pragma unroll
    for (int u = 0; u < 64; ++u) kp[u * 64] = sv[u];
  }
}

// ---------------- attention phase C v2: MFMA softmax(q) @ context ----------------
// grid 1024 ; block 256 = 4 waves. qs (A) packed bf16 row-major-by-n; Cm (B) transposed
// bf16 (cmt[e][d^swz]). Wave w computes out rows n in [w*16,w*16+16). D/Dinv in f32
// exactly as before (qs f32 weights x f32 Ksum-prefix).
__global__ __launch_bounds__(256) void k_attnC(const u16* __restrict__ qkv, const float* __restrict__ Ksum,
                                               const float* __restrict__ KV, u16* __restrict__ att) {
  int u = blockIdx.x & 63;
  int bh = blockIdx.x >> 6;
  int head = bh & 7, batch = bh >> 3;
  int t = threadIdx.x;
  int pos = t >> 2, s = t & 3;
  __shared__ u16 cmt[4096];   // cmt[e][d^swz] = bf16(Cm[d][e])
  __shared__ u16 qst[4096];   // qst[n][d^swz] = bf16(qs[n][d])
  __shared__ float S[64];
  __shared__ float dinv[64];
  // load context rows (d=pos, e-slice s), transpose to cmt as bf16
  {
    const float* kvb = KV + (size_t)blockIdx.x * 4096 + pos * 64 + s * 16;
    float cf[16];
#pragma unroll
    for (int i4 = 0; i4 < 4; ++i4) {
      float4 c4 = *(const float4*)(kvb + i4 * 4);
      cf[i4 * 4 + 0] = c4.x; cf[i4 * 4 + 1] = c4.y; cf[i4 * 4 + 2] = c4.z; cf[i4 * 4 + 3] = c4.w;
    }
#pragma unroll
    for (int i = 0; i < 16; ++i)
      cmt[(s * 16 + i) * 64 + (pos ^ ((i & 7) << 3))] = f2b(cf[i]);
  }
  if (t < 64) S[t] = Ksum[(size_t)blockIdx.x * 64 + t];
  // softmax(q) for (pos, slice s) with 4-lane team reductions
  size_t grow = (size_t)(batch * SEQ + u * 64 + pos) * QKVW + head * DH;
  uint4 q0 = *(const uint4*)(qkv + grow + s * 16);
  uint4 q1 = *(const uint4*)(qkv + grow + s * 16 + 8);
  float q[16];
  unpk8(q0, q); unpk8(q1, q + 8);
  float mx = q[0];
#pragma unroll
  for (int i = 1; i < 16; ++i) mx = fmaxf(mx, q[i]);
  mx = fmaxf(mx, __shfl_xor(mx, 1));
  mx = fmaxf(mx, __shfl_xor(mx, 2));
  float sum = 0.0f;
#pragma unroll
  for (int i = 0; i < 16; ++i) { q[i] = expf(q[i] - mx); sum += q[i]; }
  sum += __shfl_xor(sum, 1);
  sum += __shfl_xor(sum, 2);
  float scale = 0.125f / sum;  // * e^-0.5 with e=64
#pragma unroll
  for (int i = 0; i < 16; ++i) q[i] *= scale;
  // pack qs to LDS (2 x uint4, swizzled bases stay 16B-contiguous)
  {
    uint4 pa, pb;
    pa.x = (unsigned)f2b(q[0]) | ((unsigned)f2b(q[1]) << 16);
    pa.y = (unsigned)f2b(q[2]) | ((unsigned)f2b(q[3]) << 16);
    pa.z = (unsigned)f2b(q[4]) | ((unsigned)f2b(q[5]) << 16);
    pa.w = (unsigned)f2b(q[6]) | ((unsigned)f2b(q[7]) << 16);
    pb.x = (unsigned)f2b(q[8]) | ((unsigned)f2b(q[9]) << 16);
    pb.y = (unsigned)f2b(q[10]) | ((unsigned)f2b(q[11]) << 16);
    pb.z = (unsigned)f2b(q[12]) | ((unsigned)f2b(q[13]) << 16);
    pb.w = (unsigned)f2b(q[14]) | ((unsigned)f2b(q[15]) << 16);
    int Xp = (pos & 7) << 3;
    *(uint4*)(qst + pos * 64 + ((s * 16) ^ Xp)) = pa;
    *(uint4*)(qst + pos * 64 + ((s * 16 + 8) ^ Xp)) = pb;
  }
  __syncthreads();  // cmt, qst, S ready
  // D (f32, unchanged semantics)
  float Dp = 0.0f;
#pragma unroll
  for (int i = 0; i < 16; ++i) Dp += q[i] * S[s * 16 + i];
  Dp += __shfl_xor(Dp, 1);
  Dp += __shfl_xor(Dp, 2);
  if (s == 0) dinv[pos] = 1.0f / fmaxf(Dp, 1e-3f);
  // MFMA: out[n][e] = sum_d qs[n][d] * Cm[d][e]
  int w = t >> 6, l = t & 63;
  int X = (l & 7) << 3;
  int nl = w * 16 + (l & 15);
  floatx4 acc[4];
#pragma unroll
  for (int nf = 0; nf < 4; ++nf)
#pragma unroll
    for (int r = 0; r < 4; ++r) acc[nf][r] = 0.0f;
#pragma unroll
  for (int kc = 0; kc < 2; ++kc) {
    int doff = kc * 32 + (l >> 4) * 8;
    bf16x8 afr = *(const bf16x8*)(qst + nl * 64 + (doff ^ X));
#pragma unroll
    for (int nf = 0; nf < 4; ++nf) {
      bf16x8 bfr = *(const bf16x8*)(cmt + (nf * 16 + (l & 15)) * 64 + (doff ^ X));
      acc[nf] = __builtin_amdgcn_mfma_f32_16x16x32_bf16(afr, bfr, acc[nf], 0, 0, 0);
    }
  }
  __syncthreads();  // dinv ready
  u16* ob = att + (size_t)(batch * SEQ + u * 64) * DIM + head * DH;
#pragma unroll
  for (int r = 0; r < 4; ++r) {
    int n = w * 16 + (l >> 4) * 4 + r;
    float dv = dinv[n];
#pragma unroll
    for (int nf = 0; nf < 4; ++nf)
      ob[(size_t)n * DIM + nf * 16 + (l & 15)] = f2b(acc[nf][r] * dv);
  }
}

// ---------------- host orchestration ----------------
extern "C" void kernel_launch(void* const* d_in, const int* in_sizes, int n_in,
                              void* d_out, int out_size, void* d_ws, size_t ws_size,
                              hipStream_t stream) {
  (void)in_sizes; (void)n_in; (void)out_size; (void)ws_size;
  const void* x_in = d_in[0];
  const void* ln1_g = d_in[1];
  const void* ln1_b = d_in[2];
  const void* wq = d_in[3];
  const void* wk = d_in[4];
  const void* wv = d_in[5];
  const void* wo = d_in[6];
  const void* bo = d_in[7];
  const void* ln2_g = d_in[8];
  const void* ln2_b = d_in[9];
  const void* w1 = d_in[10];
  const void* b1 = d_in[11];
  const void* w2 = d_in[12];
  const void* b2 = d_in[13];

  char* ws = (char*)d_ws;
  float* xf = (float*)(ws);              // 16 MiB f32 residual
  u16* h = (u16*)(ws + 16777216);        // 8 MiB bf16
  u16* region = (u16*)(ws + 25165824);   // 32 MiB: qkv (24 MiB) / gb (32 MiB)
  float* Ksum = (float*)(ws + 58720256); // 256 KiB
  float* KV = (float*)(ws + 58982400);   // 16 MiB
  u16* WR = (u16*)(ws + 75759616);       // 24 MiB repacked weights
  int* dt = (int*)(ws + 100925440);      // dtype flag
  u16* qkv = region;
  u16* gb = region;

  auto WqkvR = [&](int i) { return WR + (size_t)i * LSTRIDE + 0; };
  auto WoR   = [&](int i) { return WR + (size_t)i * LSTRIDE + 786432; };
  auto W1R   = [&](int i) { return WR + (size_t)i * LSTRIDE + 1048576; };
  auto W2R   = [&](int i) { return WR + (size_t)i * LSTRIDE + 2097152; };

  k_detect<<<dim3(1), dim3(1), 0, stream>>>(ln1_g, dt);

  const int nx = ROWS * DIM;
  k_x2f<<<dim3((nx + 255) / 256), dim3(256), 0, stream>>>(x_in, xf, nx, dt);

  k_repackQ<<<dim3(16, 8, 16), dim3(256), 0, stream>>>(wq, wk, wv, wo, WR, dt);
  k_repackF1<<<dim3(16, 32, 4), dim3(256), 0, stream>>>(w1, WR, dt);
  k_repackF2<<<dim3(64, 8, 4), dim3(256), 0, stream>>>(w2, WR, dt);

  for (int i = 0; i < 4; ++i) {
    // PreNorm(attn)
    k_ln<<<dim3(ROWS), dim3(256), 0, stream>>>(xf, ln1_g, ln1_b, (long)i * DIM, h, dt);
    // fused QKV gemm: [8192,512] @ [512,1536]
    k_g8a<<<dim3(32, 6), dim3(512), 0, stream>>>(h, WqkvR(i), qkv, dt);
    k_attnA<<<dim3(1024), dim3(256), 0, stream>>>(qkv, Ksum, KV);
    k_scan2<<<dim3(1024), dim3(64), 0, stream>>>(Ksum, KV);
    k_attnC<<<dim3(1024), dim3(256), 0, stream>>>(qkv, Ksum, KV, h);  // att -> h
    // x += att @ wo + bo  (N=512, K=512)
    k_gemm3<512><<<dim3(64, 8), dim3(256), 0, stream>>>(h, WoR(i), bo, (long)i * DIM, xf, xf, dt);
    // PreNorm(FF)
    k_ln<<<dim3(ROWS), dim3(256), 0, stream>>>(xf, ln2_g, ln2_b, (long)i * DIM, h, dt);
    // FF up: [8192,512] @ [512,2048] + bias + gelu
    k_g8b<<<dim3(32, 8), dim3(512), 0, stream>>>(h, W1R(i), b1, (long)i * FFDIM, gb, dt);
    // FF down: [8192,2048] @ [2048,512] + bias + residual (N=512, K=2048)
    k_gemm3<2048><<<dim3(64, 8), dim3(256), 0, stream>>>(gb, W2R(i), b2, (long)i * DIM, xf, xf, dt);
  }

  k_store<<<dim3((nx + 255) / 256), dim3(256), 0, stream>>>(xf, d_out, nx, dt);
}